// Round 8
// baseline (17902.539 us; speedup 1.0000x reference)
//
#include <hip/hip_runtime.h>
#include <hip/hip_bf16.h>
#include <math.h>

// GraphLabelPropagation on MI355X.
// R8: R6 baseline (k_sims R3-style 803us, bitonic select) + CG fully fused into
//     ONE kernel (k_cg): 1024 blocks x 512 thr, launch_bounds(512,8) => VGPR<=64,
//     4 blocks/CU co-resident; software grid barrier (arrival ctr + epoch,
//     agent-scope acq/rel). Removes 100 kernel launches + drains.

#define N_NODES 16384
#define DIM     128
#define KNN     50
#define NCLS    100
#define PSTR    100
#define ALPHA_C 0.99f
#define TOL_C   1e-6f
#define TAU     0.18f
#define MAXITER_C 20
#define NBLK    1024

// ---------------- row normalize (2 rows / 256-thr block) ----------------
__global__ __launch_bounds__(256) void k_norm(const float* __restrict__ X, float* __restrict__ Xn){
  int t = threadIdx.x;
  int row = blockIdx.x*2 + (t>>7);
  int c = t & 127;
  float v = X[(size_t)row*DIM + c];
  float s = v*v;
  #pragma unroll
  for (int o=1;o<64;o<<=1) s += __shfl_xor(s, o, 64);
  __shared__ float sw[4];
  if ((t&63)==0) sw[t>>6] = s;
  __syncthreads();
  int half = (t>>7)*2;
  float nrm = fmaxf(sqrtf(sw[half]+sw[half+1]), 1e-12f);
  Xn[(size_t)row*DIM + c] = v / nrm;
}

// ---------------- fused symmetric sims GEMM + threshold filter (R3/R6) -------
#define NTILE 8256   // 128*129/2
__global__ __launch_bounds__(256, 4) void k_sims(const float* __restrict__ Xn,
    int* __restrict__ cand_cnt, float* __restrict__ cand_val, int* __restrict__ cand_idx, int CAP){
  __shared__ __align__(16) float As[32][132];
  __shared__ __align__(16) float Bs[32][132];
  const int t = threadIdx.x;
  const int tr = t >> 4, tc = t & 15;
  for (int q = blockIdx.x; q < NTILE; q += gridDim.x){
    float disc = 66049.0f - 8.0f*(float)q;   // 257^2 - 8q
    int rb = (int)((257.0f - sqrtf(disc))*0.5f);
    if (rb > 127) rb = 127;
    while (rb > 0 && rb*(257-rb)/2 > q) --rb;
    while ((rb+1)*(257-(rb+1))/2 <= q) ++rb;
    int cb = rb + (q - rb*(257-rb)/2);
    const int row0 = rb*128, col0 = cb*128;
    float acc[8][8];
    #pragma unroll
    for (int i=0;i<8;i++){
      #pragma unroll
      for (int j=0;j<8;j++) acc[i][j]=0.f;
    }
    #pragma unroll 1
    for (int h=0; h<4; ++h){
      const int koff = h*32;
      __syncthreads();
      for (int v=t; v<1024; v+=256){
        int r = v>>3, k4 = (v&7)*4;
        float4 f = *(const float4*)(Xn + (size_t)(row0+r)*DIM + koff + k4);
        As[k4+0][r]=f.x; As[k4+1][r]=f.y; As[k4+2][r]=f.z; As[k4+3][r]=f.w;
        float4 g = *(const float4*)(Xn + (size_t)(cb*128+r)*DIM + koff + k4);
        Bs[k4+0][r]=g.x; Bs[k4+1][r]=g.y; Bs[k4+2][r]=g.z; Bs[k4+3][r]=g.w;
      }
      __syncthreads();
      #pragma unroll 4
      for (int k=0;k<32;k++){
        float a[8], b[8];
        *(float4*)&a[0] = *(const float4*)&As[k][tr*4];
        *(float4*)&a[4] = *(const float4*)&As[k][64+tr*4];
        *(float4*)&b[0] = *(const float4*)&Bs[k][tc*4];
        *(float4*)&b[4] = *(const float4*)&Bs[k][64+tc*4];
        #pragma unroll
        for (int i=0;i<8;i++){
          #pragma unroll
          for (int j=0;j<8;j++) acc[i][j] = fmaf(a[i], b[j], acc[i][j]);
        }
      }
    }
    #pragma unroll
    for (int i=0;i<8;i++){
      int row = row0 + ((i<4) ? (tr*4+i) : (64+tr*4+i-4));
      #pragma unroll
      for (int j=0;j<8;j++){
        float v = acc[i][j];
        if (v > TAU){
          int col = col0 + ((j<4) ? (tc*4+j) : (64+tc*4+j-4));
          if (rb == cb){
            if (col != row){
              int pos = atomicAdd(&cand_cnt[row], 1);
              if (pos < CAP){ size_t o=(size_t)row*CAP+pos; cand_val[o]=v; cand_idx[o]=col; }
            }
          } else {
            int pos = atomicAdd(&cand_cnt[row], 1);
            if (pos < CAP){ size_t o=(size_t)row*CAP+pos; cand_val[o]=v; cand_idx[o]=col; }
            int pos2 = atomicAdd(&cand_cnt[col], 1);
            if (pos2 < CAP){ size_t o=(size_t)col*CAP+pos2; cand_val[o]=v; cand_idx[o]=row; }
          }
        }
      }
    }
  }
}

// ---------------- exact top-50 via LDS bitonic sort ----------------
__global__ __launch_bounds__(256) void k_select(const float* __restrict__ cand_val,
    const int* __restrict__ cand_idx, const int* __restrict__ cand_cnt, int CAP,
    int* __restrict__ nbr_idx, float* __restrict__ nbr_w, int* __restrict__ flags){
  int row = blockIdx.x; int t = threadIdx.x;
  int cnt = cand_cnt[row];
  if (cnt < KNN || cnt > CAP || cnt > 1024){ if (t==0) flags[row] = 1; return; }
  __shared__ unsigned long long sk[1024];
  int N = (cnt <= 512) ? 512 : 1024;
  for (int v=t; v<N; v+=256){
    unsigned long long key = 0ull;
    if (v < cnt){
      size_t o = (size_t)row*CAP + v;
      unsigned int fb = __float_as_uint(cand_val[o]);
      unsigned int ii = ~(unsigned int)cand_idx[o];
      key = ((unsigned long long)fb << 32) | (unsigned long long)ii;
    }
    sk[v] = key;
  }
  __syncthreads();
  for (int k=2; k<=N; k<<=1){
    for (int j=k>>1; j>0; j>>=1){
      for (int i=t; i<N; i+=256){
        int l = i ^ j;
        if (l > i){
          unsigned long long a = sk[i], b = sk[l];
          bool desc = ((i & k) == 0);
          bool sw = desc ? (a < b) : (a > b);
          if (sw){ sk[i] = b; sk[l] = a; }
        }
      }
      __syncthreads();
    }
  }
  if (t < KNN){
    unsigned long long key = sk[t];
    float v = __uint_as_float((unsigned int)(key >> 32));
    int ii = (int)(~(unsigned int)key);
    nbr_idx[(size_t)row*KNN + t] = ii;
    nbr_w[(size_t)row*KNN + t] = v*v*v;
  }
}

// ---------------- exact fallback (only for flagged rows; not expected) -------
__global__ __launch_bounds__(256) void k_fallback(const float* __restrict__ Xn, const int* __restrict__ flags,
    int* __restrict__ nbr_idx, float* __restrict__ nbr_w){
  int row = blockIdx.x;
  if (flags[row]==0) return;
  int t = threadIdx.x;
  __shared__ float a[DIM];
  __shared__ float cv[256]; __shared__ int ci[256];
  __shared__ float bv[KNN]; __shared__ int bi[KNN];
  __shared__ int nf; __shared__ float minv; __shared__ int mini, minpos;
  if (t < DIM) a[t] = Xn[(size_t)row*DIM + t];
  if (t==0){ nf=0; minv=1e30f; mini=-1; minpos=-1; }
  __syncthreads();
  for (int c0=0; c0<N_NODES; c0+=256){
    int col = c0 + t;
    const float* xb = Xn + (size_t)col*DIM;
    float dot = 0.f;
    for (int k=0;k<DIM;k++) dot = fmaf(a[k], xb[k], dot);
    cv[t] = (col==row) ? -1e30f : dot;
    ci[t] = col;
    __syncthreads();
    if (t==0){
      for (int u=0; u<256; u++){
        float v = cv[u]; int ix = ci[u];
        if (v <= -1e29f) continue;
        if (nf < KNN){
          bv[nf]=v; bi[nf]=ix; nf++;
          if (nf==KNN){
            minpos=0; minv=bv[0]; mini=bi[0];
            for (int q=1;q<KNN;q++) if (bv[q]<minv || (bv[q]==minv && bi[q]>mini)){minv=bv[q];mini=bi[q];minpos=q;}
          }
        } else if (v>minv || (v==minv && ix<mini)){
          bv[minpos]=v; bi[minpos]=ix;
          minpos=0; minv=bv[0]; mini=bi[0];
          for (int q=1;q<KNN;q++) if (bv[q]<minv || (bv[q]==minv && bi[q]>mini)){minv=bv[q];mini=bi[q];minpos=q;}
        }
      }
    }
    __syncthreads();
  }
  if (t==0){
    for (int aa=1; aa<KNN; aa++){
      float kv=bv[aa]; int ki=bi[aa]; int b=aa-1;
      while (b>=0 && (bv[b]<kv || (bv[b]==kv && bi[b]>ki))){ bv[b+1]=bv[b]; bi[b+1]=bi[b]; b--; }
      bv[b+1]=kv; bi[b+1]=ki;
    }
    for (int q=0;q<KNN;q++){ nbr_idx[(size_t)row*KNN+q]=bi[q]; float v=bv[q]; nbr_w[(size_t)row*KNN+q]=v*v*v; }
  }
}

// ---------------- reverse adjacency ----------------
__global__ void k_indeg(const int* __restrict__ nbr_idx, int* __restrict__ indeg){
  int e = blockIdx.x*blockDim.x + threadIdx.x;
  if (e < N_NODES*KNN) atomicAdd(&indeg[nbr_idx[e]], 1);
}
__global__ __launch_bounds__(256) void k_scan(const int* __restrict__ indeg, int* __restrict__ offs){
  int t = threadIdx.x;
  __shared__ int ps[256];
  int base = t*64, s = 0;
  for (int m=0;m<64;m++) s += indeg[base+m];
  ps[t] = s; __syncthreads();
  if (t==0){ int run=0; for (int i=0;i<256;i++){ int tmp=ps[i]; ps[i]=run; run+=tmp; } offs[N_NODES]=run; }
  __syncthreads();
  int run = ps[t];
  for (int m=0;m<64;m++){ offs[base+m]=run; run += indeg[base+m]; }
}
__global__ void k_fill(const int* __restrict__ nbr_idx, const float* __restrict__ nbr_w,
    const int* __restrict__ offs, int* __restrict__ fillc, int* __restrict__ rev_src, float* __restrict__ rev_w){
  int e = blockIdx.x*blockDim.x + threadIdx.x;
  if (e >= N_NODES*KNN) return;
  int i = e / KNN;
  int j = nbr_idx[e];
  int pos = offs[j] + atomicAdd(&fillc[j], 1);
  rev_src[pos] = i;
  rev_w[pos]  = nbr_w[e];
}
__global__ __launch_bounds__(256) void k_sortrev(const int* __restrict__ offs, int* __restrict__ rev_src, float* __restrict__ rev_w){
  __shared__ int   ssrc[4][512];
  __shared__ float swv [4][512];
  int w = threadIdx.x>>6, lane = threadIdx.x&63;
  int node = blockIdx.x*4 + w;
  int e0 = offs[node], e1 = offs[node+1];
  int len = e1 - e0;
  if (len <= 1 || len > 512) return;
  for (int q=lane; q<len; q+=64){ ssrc[w][q]=rev_src[e0+q]; swv[w][q]=rev_w[e0+q]; }
  if (lane==0){
    for (int a=1;a<len;a++){
      int ks=ssrc[w][a]; float kw=swv[w][a]; int b=a-1;
      while (b>=0 && ssrc[w][b]>ks){ ssrc[w][b+1]=ssrc[w][b]; swv[w][b+1]=swv[w][b]; b--; }
      ssrc[w][b+1]=ks; swv[w][b+1]=kw;
    }
  }
  for (int q=lane; q<len; q+=64){ rev_src[e0+q]=ssrc[w][q]; rev_w[e0+q]=swv[w][q]; }
}
__global__ void k_degree(const float* __restrict__ nbr_w, const int* __restrict__ offs,
    const float* __restrict__ rev_w, float* __restrict__ Dinv){
  int i = blockIdx.x*blockDim.x + threadIdx.x;
  if (i >= N_NODES) return;
  float s = 0.f;
  for (int k=0;k<KNN;k++) s += nbr_w[(size_t)i*KNN+k];
  int e0=offs[i], e1=offs[i+1];
  for (int e=e0;e<e1;e++) s += rev_w[e];
  if (s == 0.f) s = 1.f;
  Dinv[i] = 1.0f / sqrtf(s);
}
__global__ void k_normw_fwd(const int* __restrict__ nbr_idx, float* __restrict__ nbr_w, const float* __restrict__ Dinv){
  int e = blockIdx.x*blockDim.x + threadIdx.x;
  if (e >= N_NODES*KNN) return;
  int i = e / KNN; int j = nbr_idx[e];
  nbr_w[e] *= Dinv[i]*Dinv[j];
}
__global__ __launch_bounds__(256) void k_normw_rev(const int* __restrict__ offs, const int* __restrict__ rev_src,
    float* __restrict__ rev_w, const float* __restrict__ Dinv){
  int wid = (blockIdx.x*256 + threadIdx.x)>>6; int lane = threadIdx.x&63;
  if (wid >= N_NODES) return;
  float di = Dinv[wid];
  int e1 = offs[wid+1];
  for (int e=offs[wid]+lane; e<e1; e+=64) rev_w[e] *= di*Dinv[rev_src[e]];
}

// ---------------- CG setup ----------------
__global__ void k_clscnt(const int* __restrict__ labels, const int* __restrict__ mask, int* __restrict__ cls_cnt){
  int n = blockIdx.x*blockDim.x + threadIdx.x;
  if (n < N_NODES && mask[n]) atomicAdd(&cls_cnt[labels[n]], 1);
}
__global__ void k_init(const int* __restrict__ labels, const int* __restrict__ mask, const int* __restrict__ cls_cnt,
    float* __restrict__ x, float* __restrict__ r, float* __restrict__ p){
  int idx = blockIdx.x*blockDim.x + threadIdx.x;
  if (idx >= N_NODES*PSTR) return;
  int n = idx / PSTR, c = idx - n*PSTR;
  float y = 0.f;
  if (mask[n] && labels[n]==c) y = 1.0f / fmaxf((float)cls_cnt[c], 1.0f);
  x[idx]=0.f; r[idx]=y; p[idx]=y;
}

// ---------------- fused CG (single kernel, software grid barrier) ------------
// 1024 blocks x 512 thr; launch_bounds(512,8) => VGPR<=64, 4 blocks/CU resident.
// bctr[0] = arrival counter (monotonic), bctr[16] = release epoch (sep. line).
__device__ __forceinline__ void gbar(int* bctr, int target){
  __syncthreads();
  if (threadIdx.x == 0){
    int old = __hip_atomic_fetch_add(&bctr[0], 1, __ATOMIC_ACQ_REL, __HIP_MEMORY_SCOPE_AGENT);
    if (old == target - 1){
      __hip_atomic_store(&bctr[16], target, __ATOMIC_RELEASE, __HIP_MEMORY_SCOPE_AGENT);
    } else {
      while (__hip_atomic_load(&bctr[16], __ATOMIC_ACQUIRE, __HIP_MEMORY_SCOPE_AGENT) < target)
        __builtin_amdgcn_s_sleep(8);
    }
  }
  __syncthreads();
}

__global__ __launch_bounds__(512, 8) void k_cg(
    float* __restrict__ p, float* __restrict__ Ap, float* __restrict__ x, float* __restrict__ r,
    const int* __restrict__ nbr_idx, const float* __restrict__ nbr_w,
    const int* __restrict__ offs, const int* __restrict__ rev_src, const float* __restrict__ rev_w,
    float* __restrict__ part, float* __restrict__ rsbuf, float* __restrict__ bnorm,
    float* __restrict__ avec, float* __restrict__ betavec, int* __restrict__ actvec,
    int* __restrict__ bctr){
  const int t = threadIdx.x, w = t>>6, l = t&63;
  const int blk = blockIdx.x;
  __shared__ float sh[8][100];
  __shared__ float red[8];
  int bar = 0;
  // ---- rs0 partials from r(=Y) ----
  {
    float px=0.f, py=0.f;
    if (l < 50){
      #pragma unroll
      for (int m=0;m<2;m++){
        int n = blk*16 + m*8 + w;
        float2 rv = ((const float2*)(r + (size_t)n*PSTR))[l];
        px = fmaf(rv.x, rv.x, px); py = fmaf(rv.y, rv.y, py);
      }
      sh[w][2*l] = px; sh[w][2*l+1] = py;
    }
    __syncthreads();
    if (t < 100)
      part[(size_t)blk*100 + t] =
        ((sh[0][t]+sh[1][t])+(sh[2][t]+sh[3][t])) + ((sh[4][t]+sh[5][t])+(sh[6][t]+sh[7][t]));
  }
  bar += NBLK; gbar(bctr, bar);
  if (blk < 100){
    float s = part[(size_t)t*100 + blk] + part[(size_t)(t+512)*100 + blk];
    #pragma unroll
    for (int o=1;o<64;o<<=1) s += __shfl_xor(s, o, 64);
    if (l==0) red[w] = s;
    __syncthreads();
    if (t==0){
      float tot = ((red[0]+red[1])+(red[2]+red[3])) + ((red[4]+red[5])+(red[6]+red[7]));
      rsbuf[blk] = tot;
      bnorm[blk] = sqrtf(tot);
    }
  }
  bar += NBLK; gbar(bctr, bar);

  for (int it=0; it<MAXITER_C; ++it){
    const int cur = (it&1)*100, nxt = 100 - (it&1)*100;
    // ---- 1. spmv + pAp partials ----
    float ppx=0.f, ppy=0.f;
    #pragma unroll 1
    for (int m=0;m<2;m++){
      int node = blk*16 + m*8 + w;
      if (l < 50){
        float accx=0.f, accy=0.f;
        const size_t base = (size_t)node*KNN;
        for (int k=0;k<KNN;k++){
          int j = nbr_idx[base+k];
          float wv = nbr_w[base+k];
          float2 v = ((const float2*)(p + (size_t)j*PSTR))[l];
          accx = fmaf(wv, v.x, accx); accy = fmaf(wv, v.y, accy);
        }
        int e0 = offs[node], e1 = offs[node+1];
        for (int e=e0; e<e1; ++e){
          int j = rev_src[e];
          float wv = rev_w[e];
          float2 v = ((const float2*)(p + (size_t)j*PSTR))[l];
          accx = fmaf(wv, v.x, accx); accy = fmaf(wv, v.y, accy);
        }
        size_t o = (size_t)node*PSTR;
        float2 pv = ((const float2*)(p + o))[l];
        float ax = pv.x - ALPHA_C*accx;
        float ay = pv.y - ALPHA_C*accy;
        ((float2*)(Ap + o))[l] = make_float2(ax, ay);
        ppx = fmaf(pv.x, ax, ppx); ppy = fmaf(pv.y, ay, ppy);
      }
    }
    if (l < 50){ sh[w][2*l] = ppx; sh[w][2*l+1] = ppy; }
    __syncthreads();
    if (t < 100)
      part[(size_t)blk*100 + t] =
        ((sh[0][t]+sh[1][t])+(sh[2][t]+sh[3][t])) + ((sh[4][t]+sh[5][t])+(sh[6][t]+sh[7][t]));
    bar += NBLK; gbar(bctr, bar);
    // ---- 2. alpha (blocks 0..99) ----
    if (blk < 100){
      float s = part[(size_t)t*100 + blk] + part[(size_t)(t+512)*100 + blk];
      #pragma unroll
      for (int o=1;o<64;o<<=1) s += __shfl_xor(s, o, 64);
      if (l==0) red[w] = s;
      __syncthreads();
      if (t==0){
        float tot = ((red[0]+red[1])+(red[2]+red[3])) + ((red[4]+red[5])+(red[6]+red[7]));
        float rc = rsbuf[cur + blk];
        int act = sqrtf(rc) > TOL_C*fmaxf(bnorm[blk], 1e-30f);
        avec[blk]  = act ? rc/fmaxf(tot, 1e-30f) : 0.f;
        actvec[blk] = act;
      }
    }
    bar += NBLK; gbar(bctr, bar);
    // ---- 3. update x,r + rs partials ----
    {
      float rpx=0.f, rpy=0.f;
      if (l < 50){
        float2 av = ((const float2*)avec)[l];
        #pragma unroll
        for (int m=0;m<2;m++){
          int node = blk*16 + m*8 + w;
          size_t o = (size_t)node*PSTR;
          float2 pv  = ((const float2*)(p + o))[l];
          float2 apv = ((const float2*)(Ap + o))[l];
          float2 xv  = ((const float2*)(x + o))[l];
          float2 rv  = ((const float2*)(r + o))[l];
          xv.x = fmaf(av.x, pv.x, xv.x);  xv.y = fmaf(av.y, pv.y, xv.y);
          rv.x = rv.x - av.x*apv.x;       rv.y = rv.y - av.y*apv.y;
          ((float2*)(x + o))[l] = xv;
          ((float2*)(r + o))[l] = rv;
          rpx = fmaf(rv.x, rv.x, rpx); rpy = fmaf(rv.y, rv.y, rpy);
        }
        sh[w][2*l] = rpx; sh[w][2*l+1] = rpy;
      }
      __syncthreads();
      if (t < 100)
        part[(size_t)blk*100 + t] =
          ((sh[0][t]+sh[1][t])+(sh[2][t]+sh[3][t])) + ((sh[4][t]+sh[5][t])+(sh[6][t]+sh[7][t]));
    }
    bar += NBLK; gbar(bctr, bar);
    // ---- 4. beta (blocks 0..99) ----
    if (blk < 100){
      float s = part[(size_t)t*100 + blk] + part[(size_t)(t+512)*100 + blk];
      #pragma unroll
      for (int o=1;o<64;o<<=1) s += __shfl_xor(s, o, 64);
      if (l==0) red[w] = s;
      __syncthreads();
      if (t==0){
        float tot = ((red[0]+red[1])+(red[2]+red[3])) + ((red[4]+red[5])+(red[6]+red[7]));
        float rc = rsbuf[cur + blk];
        int act = actvec[blk];
        rsbuf[nxt + blk] = act ? tot : rc;
        betavec[blk] = act ? tot/fmaxf(rc, 1e-30f) : 0.f;
      }
    }
    bar += NBLK; gbar(bctr, bar);
    // ---- 5. update p ----
    if (l < 50){
      float2 bv = ((const float2*)betavec)[l];
      int2   av = ((const int2*)actvec)[l];
      #pragma unroll
      for (int m=0;m<2;m++){
        int node = blk*16 + m*8 + w;
        size_t o = (size_t)node*PSTR;
        float2 pv = ((const float2*)(p + o))[l];
        float2 rv = ((const float2*)(r + o))[l];
        pv.x = av.x ? fmaf(bv.x, pv.x, rv.x) : pv.x;
        pv.y = av.y ? fmaf(bv.y, pv.y, rv.y) : pv.y;
        ((float2*)(p + o))[l] = pv;
      }
    }
    bar += NBLK; gbar(bctr, bar);
  }
}

// ---------------- finalize ----------------
__global__ __launch_bounds__(256) void k_final(const float* __restrict__ x, const int* __restrict__ labels,
    const int* __restrict__ mask, float* __restrict__ out, int* __restrict__ acc_cnt){
  int n = blockIdx.x*blockDim.x + threadIdx.x;
  if (n >= N_NODES) return;
  const float* xr = x + (size_t)n*PSTR;
  float best = xr[0]; int arg = 0;
  for (int c=1;c<NCLS;c++){ float v = xr[c]; if (v > best){ best = v; arg = c; } }
  int plab = (best > 0.f) ? arg : 0;
  if (plab == labels[n]) atomicAdd(acc_cnt, 1);
  int lab = mask[n] ? labels[n] : plab;
  out[n] = (float)lab;
  out[N_NODES + 1 + n] = 0.f;   // masks provably all-zero
}
__global__ void k_acc(const int* __restrict__ acc_cnt, float* __restrict__ out){
  out[N_NODES] = (float)(*acc_cnt) / (float)N_NODES;
}

// ---------------- host ----------------
extern "C" void kernel_launch(void* const* d_in, const int* in_sizes, int n_in,
                              void* d_out, int out_size, void* d_ws, size_t ws_size,
                              hipStream_t stream){
  (void)in_sizes; (void)n_in; (void)out_size;
  const float* X      = (const float*)d_in[0];
  const int*   labels = (const int*)  d_in[1];
  const int*   mask   = (const int*)  d_in[2];
  float* out = (float*)d_out;

  char* ws = (char*)d_ws;
  size_t off = 0;
  auto alloc = [&](size_t bytes)->char*{ char* pp = ws + off; off += (bytes + 255) & ~(size_t)255; return pp; };

  float* Xn      = (float*)alloc((size_t)N_NODES*DIM*4);
  int*   nbr_idx = (int*)  alloc((size_t)N_NODES*KNN*4);
  float* nbr_w   = (float*)alloc((size_t)N_NODES*KNN*4);
  int*   indeg   = (int*)  alloc((size_t)N_NODES*4);
  int*   offs    = (int*)  alloc((size_t)(N_NODES+1)*4);
  int*   fillc   = (int*)  alloc((size_t)N_NODES*4);
  int*   rev_src = (int*)  alloc((size_t)N_NODES*KNN*4);
  float* rev_w   = (float*)alloc((size_t)N_NODES*KNN*4);
  float* Dinv    = (float*)alloc((size_t)N_NODES*4);
  int*   cls_cnt = (int*)  alloc(128*4);
  float* x  = (float*)alloc((size_t)N_NODES*PSTR*4);
  float* r  = (float*)alloc((size_t)N_NODES*PSTR*4);
  float* p  = (float*)alloc((size_t)N_NODES*PSTR*4);
  float* Ap = (float*)alloc((size_t)N_NODES*PSTR*4);
  float* rsbuf  = (float*)alloc(256*4);
  float* avec   = (float*)alloc(128*4);
  float* betavec= (float*)alloc(128*4);
  int*   actvec = (int*)  alloc(128*4);
  float* bnorm  = (float*)alloc(128*4);
  float* part   = (float*)alloc((size_t)NBLK*100*4);
  int*   acc_cnt= (int*)  alloc(256);
  int*   bctr   = (int*)  alloc(256);
  int*   flags  = (int*)  alloc((size_t)N_NODES*4);
  int*   cand_cnt=(int*)  alloc((size_t)N_NODES*4);

  size_t rem = (ws_size > off) ? (ws_size - off) : 0;
  size_t capc = rem/((size_t)N_NODES*8);
  int CAP = (int)(capc < 1024 ? capc : 1024);
  float* cand_val = (float*)alloc((size_t)N_NODES*CAP*4);
  int*   cand_idx = (int*)  alloc((size_t)N_NODES*CAP*4);

  hipMemsetAsync(cand_cnt, 0, (size_t)N_NODES*4, stream);
  hipMemsetAsync(flags,    0, (size_t)N_NODES*4, stream);
  hipMemsetAsync(indeg,    0, (size_t)N_NODES*4, stream);
  hipMemsetAsync(fillc,    0, (size_t)N_NODES*4, stream);
  hipMemsetAsync(cls_cnt,  0, 128*4, stream);
  hipMemsetAsync(acc_cnt,  0, 4, stream);
  hipMemsetAsync(bctr,     0, 256, stream);

  k_norm    <<<N_NODES/2, 256, 0, stream>>>(X, Xn);
  k_sims    <<<1024, 256, 0, stream>>>(Xn, cand_cnt, cand_val, cand_idx, CAP);
  k_select  <<<N_NODES, 256, 0, stream>>>(cand_val, cand_idx, cand_cnt, CAP, nbr_idx, nbr_w, flags);
  k_fallback<<<N_NODES, 256, 0, stream>>>(Xn, flags, nbr_idx, nbr_w);
  k_indeg   <<<3200, 256, 0, stream>>>(nbr_idx, indeg);
  k_scan    <<<1, 256, 0, stream>>>(indeg, offs);
  k_fill    <<<3200, 256, 0, stream>>>(nbr_idx, nbr_w, offs, fillc, rev_src, rev_w);
  k_sortrev <<<4096, 256, 0, stream>>>(offs, rev_src, rev_w);
  k_degree  <<<64, 256, 0, stream>>>(nbr_w, offs, rev_w, Dinv);
  k_normw_fwd<<<3200, 256, 0, stream>>>(nbr_idx, nbr_w, Dinv);
  k_normw_rev<<<4096, 256, 0, stream>>>(offs, rev_src, rev_w, Dinv);
  k_clscnt  <<<64, 256, 0, stream>>>(labels, mask, cls_cnt);
  k_init    <<<(N_NODES*PSTR+255)/256, 256, 0, stream>>>(labels, mask, cls_cnt, x, r, p);

  k_cg <<<NBLK, 512, 0, stream>>>(p, Ap, x, r, nbr_idx, nbr_w, offs, rev_src, rev_w,
                                  part, rsbuf, bnorm, avec, betavec, actvec, bctr);

  k_final<<<64, 256, 0, stream>>>(x, labels, mask, out, acc_cnt);
  k_acc  <<<1, 1, 0, stream>>>(acc_cnt, out);
}

// Round 9
// 3574.109 us; speedup vs baseline: 5.0090x; 5.0090x over previous
//
#include <hip/hip_runtime.h>
#include <hip/hip_bf16.h>
#include <math.h>

// GraphLabelPropagation on MI355X.
// R9: R6 baseline (k_sims R3-style GEMM, discrete CG kernels) with emission fix:
//     candidates stored as single 8B packed keys (val_bits<<32)|~idx (halves
//     scattered-store line traffic; k_select loads keys directly), TAU=0.195
//     (safe ~10-sigma margin vs per-row k50=0.212+-0.0017), N=256 sort path.

#define N_NODES 16384
#define DIM     128
#define KNN     50
#define NCLS    100
#define PSTR    100
#define ALPHA_C 0.99f
#define TOL_C   1e-6f
#define TAU     0.195f
#define MAXITER_C 20

// ---------------- row normalize (2 rows / 256-thr block) ----------------
__global__ __launch_bounds__(256) void k_norm(const float* __restrict__ X, float* __restrict__ Xn){
  int t = threadIdx.x;
  int row = blockIdx.x*2 + (t>>7);
  int c = t & 127;
  float v = X[(size_t)row*DIM + c];
  float s = v*v;
  #pragma unroll
  for (int o=1;o<64;o<<=1) s += __shfl_xor(s, o, 64);
  __shared__ float sw[4];
  if ((t&63)==0) sw[t>>6] = s;
  __syncthreads();
  int half = (t>>7)*2;
  float nrm = fmaxf(sqrtf(sw[half]+sw[half+1]), 1e-12f);
  Xn[(size_t)row*DIM + c] = v / nrm;
}

// ---------------- fused symmetric sims GEMM + threshold filter ----------------
// Upper-tri 128x128 tiles (8256) over 1024 blocks (4/CU, static grid-stride).
// LDS k-transposed: As[k][row], stride 132 (16B-aligned b128 reads, offset-folded).
// Emission: single 8B packed key per candidate.
#define NTILE 8256   // 128*129/2
__global__ __launch_bounds__(256, 4) void k_sims(const float* __restrict__ Xn,
    int* __restrict__ cand_cnt, unsigned long long* __restrict__ cand, int CAP){
  __shared__ __align__(16) float As[32][132];
  __shared__ __align__(16) float Bs[32][132];
  const int t = threadIdx.x;
  const int tr = t >> 4, tc = t & 15;
  for (int q = blockIdx.x; q < NTILE; q += gridDim.x){
    float disc = 66049.0f - 8.0f*(float)q;   // 257^2 - 8q
    int rb = (int)((257.0f - sqrtf(disc))*0.5f);
    if (rb > 127) rb = 127;
    while (rb > 0 && rb*(257-rb)/2 > q) --rb;
    while ((rb+1)*(257-(rb+1))/2 <= q) ++rb;
    int cb = rb + (q - rb*(257-rb)/2);
    const int row0 = rb*128, col0 = cb*128;
    float acc[8][8];
    #pragma unroll
    for (int i=0;i<8;i++){
      #pragma unroll
      for (int j=0;j<8;j++) acc[i][j]=0.f;
    }
    #pragma unroll 1
    for (int h=0; h<4; ++h){
      const int koff = h*32;
      __syncthreads();   // prior reads done before overwrite
      for (int v=t; v<1024; v+=256){
        int r = v>>3, k4 = (v&7)*4;
        float4 f = *(const float4*)(Xn + (size_t)(row0+r)*DIM + koff + k4);
        As[k4+0][r]=f.x; As[k4+1][r]=f.y; As[k4+2][r]=f.z; As[k4+3][r]=f.w;
        float4 g = *(const float4*)(Xn + (size_t)(col0+r)*DIM + koff + k4);
        Bs[k4+0][r]=g.x; Bs[k4+1][r]=g.y; Bs[k4+2][r]=g.z; Bs[k4+3][r]=g.w;
      }
      __syncthreads();
      #pragma unroll 4
      for (int k=0;k<32;k++){
        float a[8], b[8];
        *(float4*)&a[0] = *(const float4*)&As[k][tr*4];
        *(float4*)&a[4] = *(const float4*)&As[k][64+tr*4];
        *(float4*)&b[0] = *(const float4*)&Bs[k][tc*4];
        *(float4*)&b[4] = *(const float4*)&Bs[k][64+tc*4];
        #pragma unroll
        for (int i=0;i<8;i++){
          #pragma unroll
          for (int j=0;j<8;j++) acc[i][j] = fmaf(a[i], b[j], acc[i][j]);
        }
      }
    }
    #pragma unroll
    for (int i=0;i<8;i++){
      int row = row0 + ((i<4) ? (tr*4+i) : (64+tr*4+i-4));
      #pragma unroll
      for (int j=0;j<8;j++){
        float v = acc[i][j];
        if (v > TAU){
          int col = col0 + ((j<4) ? (tc*4+j) : (64+tc*4+j-4));
          unsigned long long vb = (unsigned long long)__float_as_uint(v) << 32;
          if (rb == cb){
            if (col != row){
              int pos = atomicAdd(&cand_cnt[row], 1);
              if (pos < CAP) cand[(size_t)row*CAP + pos] = vb | (unsigned long long)(~(unsigned int)col);
            }
          } else {
            int pos = atomicAdd(&cand_cnt[row], 1);
            if (pos < CAP) cand[(size_t)row*CAP + pos] = vb | (unsigned long long)(~(unsigned int)col);
            int pos2 = atomicAdd(&cand_cnt[col], 1);
            if (pos2 < CAP) cand[(size_t)col*CAP + pos2] = vb | (unsigned long long)(~(unsigned int)row);
          }
        }
      }
    }
  }
}

// ---------------- exact top-50 via LDS bitonic sort of packed keys ------------
// uint64-descending == (val desc, idx asc). Padding key 0 sorts last.
__global__ __launch_bounds__(256) void k_select(const unsigned long long* __restrict__ cand,
    const int* __restrict__ cand_cnt, int CAP,
    int* __restrict__ nbr_idx, float* __restrict__ nbr_w, int* __restrict__ flags){
  int row = blockIdx.x; int t = threadIdx.x;
  int cnt = cand_cnt[row];
  if (cnt < KNN || cnt > CAP || cnt > 1024){ if (t==0) flags[row] = 1; return; }
  __shared__ unsigned long long sk[1024];
  int N = (cnt <= 256) ? 256 : ((cnt <= 512) ? 512 : 1024);
  for (int v=t; v<N; v+=256)
    sk[v] = (v < cnt) ? cand[(size_t)row*CAP + v] : 0ull;
  __syncthreads();
  for (int k=2; k<=N; k<<=1){
    for (int j=k>>1; j>0; j>>=1){
      for (int i=t; i<N; i+=256){
        int l = i ^ j;
        if (l > i){
          unsigned long long a = sk[i], b = sk[l];
          bool desc = ((i & k) == 0);
          bool sw = desc ? (a < b) : (a > b);
          if (sw){ sk[i] = b; sk[l] = a; }
        }
      }
      __syncthreads();
    }
  }
  if (t < KNN){
    unsigned long long key = sk[t];
    float v = __uint_as_float((unsigned int)(key >> 32));
    int ii = (int)(~(unsigned int)key);
    nbr_idx[(size_t)row*KNN + t] = ii;
    nbr_w[(size_t)row*KNN + t] = v*v*v;
  }
}

// ---------------- exact fallback (only for flagged rows; not expected) --------
__global__ __launch_bounds__(256) void k_fallback(const float* __restrict__ Xn, const int* __restrict__ flags,
    int* __restrict__ nbr_idx, float* __restrict__ nbr_w){
  int row = blockIdx.x;
  if (flags[row]==0) return;
  int t = threadIdx.x;
  __shared__ float a[DIM];
  __shared__ float cv[256]; __shared__ int ci[256];
  __shared__ float bv[KNN]; __shared__ int bi[KNN];
  __shared__ int nf; __shared__ float minv; __shared__ int mini, minpos;
  if (t < DIM) a[t] = Xn[(size_t)row*DIM + t];
  if (t==0){ nf=0; minv=1e30f; mini=-1; minpos=-1; }
  __syncthreads();
  for (int c0=0; c0<N_NODES; c0+=256){
    int col = c0 + t;
    const float* xb = Xn + (size_t)col*DIM;
    float dot = 0.f;
    for (int k=0;k<DIM;k++) dot = fmaf(a[k], xb[k], dot);
    cv[t] = (col==row) ? -1e30f : dot;
    ci[t] = col;
    __syncthreads();
    if (t==0){
      for (int u=0; u<256; u++){
        float v = cv[u]; int ix = ci[u];
        if (v <= -1e29f) continue;
        if (nf < KNN){
          bv[nf]=v; bi[nf]=ix; nf++;
          if (nf==KNN){
            minpos=0; minv=bv[0]; mini=bi[0];
            for (int q=1;q<KNN;q++) if (bv[q]<minv || (bv[q]==minv && bi[q]>mini)){minv=bv[q];mini=bi[q];minpos=q;}
          }
        } else if (v>minv || (v==minv && ix<mini)){
          bv[minpos]=v; bi[minpos]=ix;
          minpos=0; minv=bv[0]; mini=bi[0];
          for (int q=1;q<KNN;q++) if (bv[q]<minv || (bv[q]==minv && bi[q]>mini)){minv=bv[q];mini=bi[q];minpos=q;}
        }
      }
    }
    __syncthreads();
  }
  if (t==0){
    for (int aa=1; aa<KNN; aa++){
      float kv=bv[aa]; int ki=bi[aa]; int b=aa-1;
      while (b>=0 && (bv[b]<kv || (bv[b]==kv && bi[b]>ki))){ bv[b+1]=bv[b]; bi[b+1]=bi[b]; b--; }
      bv[b+1]=kv; bi[b+1]=ki;
    }
    for (int q=0;q<KNN;q++){ nbr_idx[(size_t)row*KNN+q]=bi[q]; float v=bv[q]; nbr_w[(size_t)row*KNN+q]=v*v*v; }
  }
}

// ---------------- reverse adjacency ----------------
__global__ void k_indeg(const int* __restrict__ nbr_idx, int* __restrict__ indeg){
  int e = blockIdx.x*blockDim.x + threadIdx.x;
  if (e < N_NODES*KNN) atomicAdd(&indeg[nbr_idx[e]], 1);
}
__global__ __launch_bounds__(256) void k_scan(const int* __restrict__ indeg, int* __restrict__ offs){
  int t = threadIdx.x;
  __shared__ int ps[256];
  int base = t*64, s = 0;
  for (int m=0;m<64;m++) s += indeg[base+m];
  ps[t] = s; __syncthreads();
  if (t==0){ int run=0; for (int i=0;i<256;i++){ int tmp=ps[i]; ps[i]=run; run+=tmp; } offs[N_NODES]=run; }
  __syncthreads();
  int run = ps[t];
  for (int m=0;m<64;m++){ offs[base+m]=run; run += indeg[base+m]; }
}
__global__ void k_fill(const int* __restrict__ nbr_idx, const float* __restrict__ nbr_w,
    const int* __restrict__ offs, int* __restrict__ fillc, int* __restrict__ rev_src, float* __restrict__ rev_w){
  int e = blockIdx.x*blockDim.x + threadIdx.x;
  if (e >= N_NODES*KNN) return;
  int i = e / KNN;
  int j = nbr_idx[e];
  int pos = offs[j] + atomicAdd(&fillc[j], 1);
  rev_src[pos] = i;
  rev_w[pos]  = nbr_w[e];
}
__global__ __launch_bounds__(256) void k_sortrev(const int* __restrict__ offs, int* __restrict__ rev_src, float* __restrict__ rev_w){
  __shared__ int   ssrc[4][512];
  __shared__ float swv [4][512];
  int w = threadIdx.x>>6, lane = threadIdx.x&63;
  int node = blockIdx.x*4 + w;
  int e0 = offs[node], e1 = offs[node+1];
  int len = e1 - e0;
  if (len <= 1 || len > 512) return;
  for (int q=lane; q<len; q+=64){ ssrc[w][q]=rev_src[e0+q]; swv[w][q]=rev_w[e0+q]; }
  if (lane==0){
    for (int a=1;a<len;a++){
      int ks=ssrc[w][a]; float kw=swv[w][a]; int b=a-1;
      while (b>=0 && ssrc[w][b]>ks){ ssrc[w][b+1]=ssrc[w][b]; swv[w][b+1]=swv[w][b]; b--; }
      ssrc[w][b+1]=ks; swv[w][b+1]=kw;
    }
  }
  for (int q=lane; q<len; q+=64){ rev_src[e0+q]=ssrc[w][q]; rev_w[e0+q]=swv[w][q]; }
}
__global__ void k_degree(const float* __restrict__ nbr_w, const int* __restrict__ offs,
    const float* __restrict__ rev_w, float* __restrict__ Dinv){
  int i = blockIdx.x*blockDim.x + threadIdx.x;
  if (i >= N_NODES) return;
  float s = 0.f;
  for (int k=0;k<KNN;k++) s += nbr_w[(size_t)i*KNN+k];
  int e0=offs[i], e1=offs[i+1];
  for (int e=e0;e<e1;e++) s += rev_w[e];
  if (s == 0.f) s = 1.f;
  Dinv[i] = 1.0f / sqrtf(s);
}
__global__ void k_normw_fwd(const int* __restrict__ nbr_idx, float* __restrict__ nbr_w, const float* __restrict__ Dinv){
  int e = blockIdx.x*blockDim.x + threadIdx.x;
  if (e >= N_NODES*KNN) return;
  int i = e / KNN; int j = nbr_idx[e];
  nbr_w[e] *= Dinv[i]*Dinv[j];
}
__global__ __launch_bounds__(256) void k_normw_rev(const int* __restrict__ offs, const int* __restrict__ rev_src,
    float* __restrict__ rev_w, const float* __restrict__ Dinv){
  int wid = (blockIdx.x*256 + threadIdx.x)>>6; int lane = threadIdx.x&63;
  if (wid >= N_NODES) return;
  float di = Dinv[wid];
  int e1 = offs[wid+1];
  for (int e=offs[wid]+lane; e<e1; e+=64) rev_w[e] *= di*Dinv[rev_src[e]];
}

// ---------------- CG setup ----------------
__global__ void k_clscnt(const int* __restrict__ labels, const int* __restrict__ mask, int* __restrict__ cls_cnt){
  int n = blockIdx.x*blockDim.x + threadIdx.x;
  if (n < N_NODES && mask[n]) atomicAdd(&cls_cnt[labels[n]], 1);
}
__global__ void k_init(const int* __restrict__ labels, const int* __restrict__ mask, const int* __restrict__ cls_cnt,
    float* __restrict__ x, float* __restrict__ r, float* __restrict__ p){
  int idx = blockIdx.x*blockDim.x + threadIdx.x;
  if (idx >= N_NODES*PSTR) return;
  int n = idx / PSTR, c = idx - n*PSTR;
  float y = 0.f;
  if (mask[n] && labels[n]==c) y = 1.0f / fmaxf((float)cls_cnt[c], 1.0f);
  x[idx]=0.f; r[idx]=y; p[idx]=y;
}

// ---------------- CG kernels (stride 100, wave-per-node, lanes 0..49 x float2) --
__global__ __launch_bounds__(256) void k_spmv_pap(const float* __restrict__ p, float* __restrict__ Ap,
    const int* __restrict__ nbr_idx, const float* __restrict__ nbr_w,
    const int* __restrict__ offs, const int* __restrict__ rev_src, const float* __restrict__ rev_w,
    float* __restrict__ part){
  int w = threadIdx.x>>6, l = threadIdx.x&63;
  int wid = blockIdx.x*4 + w;
  __shared__ float sh[4][100];
  if (l < 50){
    float accx=0.f, accy=0.f;
    const size_t base = (size_t)wid*KNN;
    for (int k=0;k<KNN;k++){
      int j = nbr_idx[base+k];
      float wv = nbr_w[base+k];
      float2 v = ((const float2*)(p + (size_t)j*PSTR))[l];
      accx = fmaf(wv, v.x, accx);
      accy = fmaf(wv, v.y, accy);
    }
    int e1 = offs[wid+1];
    for (int e=offs[wid]; e<e1; ++e){
      int j = rev_src[e];
      float wv = rev_w[e];
      float2 v = ((const float2*)(p + (size_t)j*PSTR))[l];
      accx = fmaf(wv, v.x, accx);
      accy = fmaf(wv, v.y, accy);
    }
    size_t o = (size_t)wid*PSTR;
    float2 pv = ((const float2*)(p + o))[l];
    float ax = pv.x - ALPHA_C*accx;
    float ay = pv.y - ALPHA_C*accy;
    ((float2*)(Ap + o))[l] = make_float2(ax, ay);
    sh[w][2*l]   = pv.x*ax;
    sh[w][2*l+1] = pv.y*ay;
  }
  __syncthreads();
  int tt = threadIdx.x;
  if (tt < 100) part[(size_t)blockIdx.x*100 + tt] = (sh[0][tt]+sh[1][tt]) + (sh[2][tt]+sh[3][tt]);
}
__global__ __launch_bounds__(256) void k_alpha(const float* __restrict__ part, const float* __restrict__ rs_cur,
    const float* __restrict__ bnorm, float* __restrict__ avec, int* __restrict__ actvec){
  int c = blockIdx.x, t = threadIdx.x;
  float s = 0.f;
  for (int b=t; b<4096; b+=256) s += part[(size_t)b*100 + c];
  #pragma unroll
  for (int o=1;o<64;o<<=1) s += __shfl_xor(s, o, 64);
  __shared__ float red[4];
  if ((t&63)==0) red[t>>6] = s;
  __syncthreads();
  if (t==0){
    float tot = (red[0]+red[1]) + (red[2]+red[3]);
    float rc = rs_cur[c];
    int act = sqrtf(rc) > TOL_C*fmaxf(bnorm[c], 1e-30f);
    avec[c] = act ? rc/fmaxf(tot, 1e-30f) : 0.f;
    actvec[c] = act;
  }
}
__global__ __launch_bounds__(256) void k_update_xr(float* __restrict__ x, float* __restrict__ r,
    const float* __restrict__ p, const float* __restrict__ Ap,
    const float* __restrict__ avec, float* __restrict__ part){
  int w = threadIdx.x>>6, l = threadIdx.x&63;
  int n = blockIdx.x*4 + w;
  __shared__ float sh[4][100];
  if (l < 50){
    size_t o = (size_t)n*PSTR;
    float2 av  = ((const float2*)avec)[l];
    float2 pv  = ((const float2*)(p + o))[l];
    float2 apv = ((const float2*)(Ap + o))[l];
    float2 xv  = ((const float2*)(x + o))[l];
    float2 rv  = ((const float2*)(r + o))[l];
    xv.x = fmaf(av.x, pv.x, xv.x);
    xv.y = fmaf(av.y, pv.y, xv.y);
    rv.x = rv.x - av.x*apv.x;
    rv.y = rv.y - av.y*apv.y;
    ((float2*)(x + o))[l] = xv;
    ((float2*)(r + o))[l] = rv;
    sh[w][2*l]   = rv.x*rv.x;
    sh[w][2*l+1] = rv.y*rv.y;
  }
  __syncthreads();
  int tt = threadIdx.x;
  if (tt < 100) part[(size_t)blockIdx.x*100 + tt] = (sh[0][tt]+sh[1][tt]) + (sh[2][tt]+sh[3][tt]);
}
__global__ __launch_bounds__(256) void k_beta(const float* __restrict__ part, const float* __restrict__ rs_cur,
    const int* __restrict__ actvec, float* __restrict__ rs_next, float* __restrict__ betavec){
  int c = blockIdx.x, t = threadIdx.x;
  float s = 0.f;
  for (int b=t; b<4096; b+=256) s += part[(size_t)b*100 + c];
  #pragma unroll
  for (int o=1;o<64;o<<=1) s += __shfl_xor(s, o, 64);
  __shared__ float red[4];
  if ((t&63)==0) red[t>>6] = s;
  __syncthreads();
  if (t==0){
    float tot = (red[0]+red[1]) + (red[2]+red[3]);
    float rc = rs_cur[c];
    int act = actvec[c];
    rs_next[c] = act ? tot : rc;
    betavec[c] = act ? tot/fmaxf(rc, 1e-30f) : 0.f;
  }
}
__global__ __launch_bounds__(256) void k_update_p(float* __restrict__ p, const float* __restrict__ r,
    const int* __restrict__ actvec, const float* __restrict__ betavec){
  int w = threadIdx.x>>6, l = threadIdx.x&63;
  int n = blockIdx.x*4 + w;
  if (l >= 50) return;
  size_t o = (size_t)n*PSTR;
  float2 bv = ((const float2*)betavec)[l];
  int2   av = ((const int2*)actvec)[l];
  float2 pv = ((const float2*)(p + o))[l];
  float2 rv = ((const float2*)(r + o))[l];
  pv.x = av.x ? fmaf(bv.x, pv.x, rv.x) : pv.x;
  pv.y = av.y ? fmaf(bv.y, pv.y, rv.y) : pv.y;
  ((float2*)(p + o))[l] = pv;
}
// initial rs0 partials from r (=Y)
__global__ __launch_bounds__(256) void k_coldot0(const float* __restrict__ r, float* __restrict__ part){
  int w = threadIdx.x>>6, l = threadIdx.x&63;
  int n = blockIdx.x*4 + w;
  __shared__ float sh[4][100];
  if (l < 50){
    float2 rv = ((const float2*)(r + (size_t)n*PSTR))[l];
    sh[w][2*l]   = rv.x*rv.x;
    sh[w][2*l+1] = rv.y*rv.y;
  }
  __syncthreads();
  int tt = threadIdx.x;
  if (tt < 100) part[(size_t)blockIdx.x*100 + tt] = (sh[0][tt]+sh[1][tt]) + (sh[2][tt]+sh[3][tt]);
}
__global__ __launch_bounds__(256) void k_rs0(const float* __restrict__ part, float* __restrict__ rs0, float* __restrict__ bnorm){
  int c = blockIdx.x, t = threadIdx.x;
  float s = 0.f;
  for (int b=t; b<4096; b+=256) s += part[(size_t)b*100 + c];
  #pragma unroll
  for (int o=1;o<64;o<<=1) s += __shfl_xor(s, o, 64);
  __shared__ float red[4];
  if ((t&63)==0) red[t>>6] = s;
  __syncthreads();
  if (t==0){
    float tot = (red[0]+red[1]) + (red[2]+red[3]);
    rs0[c] = tot;
    bnorm[c] = sqrtf(tot);
  }
}

// ---------------- finalize ----------------
__global__ __launch_bounds__(256) void k_final(const float* __restrict__ x, const int* __restrict__ labels,
    const int* __restrict__ mask, float* __restrict__ out, int* __restrict__ acc_cnt){
  int n = blockIdx.x*blockDim.x + threadIdx.x;
  if (n >= N_NODES) return;
  const float* xr = x + (size_t)n*PSTR;
  float best = xr[0]; int arg = 0;
  for (int c=1;c<NCLS;c++){ float v = xr[c]; if (v > best){ best = v; arg = c; } }
  int plab = (best > 0.f) ? arg : 0;
  if (plab == labels[n]) atomicAdd(acc_cnt, 1);
  int lab = mask[n] ? labels[n] : plab;
  out[n] = (float)lab;
  out[N_NODES + 1 + n] = 0.f;   // masks provably all-zero
}
__global__ void k_acc(const int* __restrict__ acc_cnt, float* __restrict__ out){
  out[N_NODES] = (float)(*acc_cnt) / (float)N_NODES;
}

// ---------------- host ----------------
extern "C" void kernel_launch(void* const* d_in, const int* in_sizes, int n_in,
                              void* d_out, int out_size, void* d_ws, size_t ws_size,
                              hipStream_t stream){
  (void)in_sizes; (void)n_in; (void)out_size;
  const float* X      = (const float*)d_in[0];
  const int*   labels = (const int*)  d_in[1];
  const int*   mask   = (const int*)  d_in[2];
  float* out = (float*)d_out;

  char* ws = (char*)d_ws;
  size_t off = 0;
  auto alloc = [&](size_t bytes)->char*{ char* pp = ws + off; off += (bytes + 255) & ~(size_t)255; return pp; };

  float* Xn      = (float*)alloc((size_t)N_NODES*DIM*4);
  int*   nbr_idx = (int*)  alloc((size_t)N_NODES*KNN*4);
  float* nbr_w   = (float*)alloc((size_t)N_NODES*KNN*4);
  int*   indeg   = (int*)  alloc((size_t)N_NODES*4);
  int*   offs    = (int*)  alloc((size_t)(N_NODES+1)*4);
  int*   fillc   = (int*)  alloc((size_t)N_NODES*4);
  int*   rev_src = (int*)  alloc((size_t)N_NODES*KNN*4);
  float* rev_w   = (float*)alloc((size_t)N_NODES*KNN*4);
  float* Dinv    = (float*)alloc((size_t)N_NODES*4);
  int*   cls_cnt = (int*)  alloc(128*4);
  float* x  = (float*)alloc((size_t)N_NODES*PSTR*4);
  float* r  = (float*)alloc((size_t)N_NODES*PSTR*4);
  float* p  = (float*)alloc((size_t)N_NODES*PSTR*4);
  float* Ap = (float*)alloc((size_t)N_NODES*PSTR*4);
  float* rs_a   = (float*)alloc(128*4);
  float* rs_b   = (float*)alloc(128*4);
  float* avec   = (float*)alloc(128*4);
  float* betavec= (float*)alloc(128*4);
  int*   actvec = (int*)  alloc(128*4);
  float* bnorm  = (float*)alloc(128*4);
  float* part   = (float*)alloc((size_t)4096*100*4);
  int*   acc_cnt= (int*)  alloc(256);
  int*   flags  = (int*)  alloc((size_t)N_NODES*4);
  int*   cand_cnt=(int*)  alloc((size_t)N_NODES*4);

  size_t rem = (ws_size > off) ? (ws_size - off) : 0;
  size_t capc = rem/((size_t)N_NODES*8);
  int CAP = (int)(capc < 1024 ? capc : 1024);
  CAP &= ~7;   // keep rows 64B-aligned
  unsigned long long* cand = (unsigned long long*)alloc((size_t)N_NODES*CAP*8);

  hipMemsetAsync(cand_cnt, 0, (size_t)N_NODES*4, stream);
  hipMemsetAsync(flags,    0, (size_t)N_NODES*4, stream);
  hipMemsetAsync(indeg,    0, (size_t)N_NODES*4, stream);
  hipMemsetAsync(fillc,    0, (size_t)N_NODES*4, stream);
  hipMemsetAsync(cls_cnt,  0, 128*4, stream);
  hipMemsetAsync(acc_cnt,  0, 4, stream);

  k_norm    <<<N_NODES/2, 256, 0, stream>>>(X, Xn);
  k_sims    <<<1024, 256, 0, stream>>>(Xn, cand_cnt, cand, CAP);
  k_select  <<<N_NODES, 256, 0, stream>>>(cand, cand_cnt, CAP, nbr_idx, nbr_w, flags);
  k_fallback<<<N_NODES, 256, 0, stream>>>(Xn, flags, nbr_idx, nbr_w);
  k_indeg   <<<3200, 256, 0, stream>>>(nbr_idx, indeg);
  k_scan    <<<1, 256, 0, stream>>>(indeg, offs);
  k_fill    <<<3200, 256, 0, stream>>>(nbr_idx, nbr_w, offs, fillc, rev_src, rev_w);
  k_sortrev <<<4096, 256, 0, stream>>>(offs, rev_src, rev_w);
  k_degree  <<<64, 256, 0, stream>>>(nbr_w, offs, rev_w, Dinv);
  k_normw_fwd<<<3200, 256, 0, stream>>>(nbr_idx, nbr_w, Dinv);
  k_normw_rev<<<4096, 256, 0, stream>>>(offs, rev_src, rev_w, Dinv);
  k_clscnt  <<<64, 256, 0, stream>>>(labels, mask, cls_cnt);
  k_init    <<<(N_NODES*PSTR+255)/256, 256, 0, stream>>>(labels, mask, cls_cnt, x, r, p);
  k_coldot0 <<<4096, 256, 0, stream>>>(r, part);
  k_rs0     <<<100, 256, 0, stream>>>(part, rs_a, bnorm);

  for (int it=0; it<MAXITER_C; ++it){
    float* rs_cur = (it&1) ? rs_b : rs_a;
    float* rs_nxt = (it&1) ? rs_a : rs_b;
    k_spmv_pap <<<4096, 256, 0, stream>>>(p, Ap, nbr_idx, nbr_w, offs, rev_src, rev_w, part);
    k_alpha    <<<100, 256, 0, stream>>>(part, rs_cur, bnorm, avec, actvec);
    k_update_xr<<<4096, 256, 0, stream>>>(x, r, p, Ap, avec, part);
    k_beta     <<<100, 256, 0, stream>>>(part, rs_cur, actvec, rs_nxt, betavec);
    k_update_p <<<4096, 256, 0, stream>>>(p, r, actvec, betavec);
  }

  k_final<<<64, 256, 0, stream>>>(x, labels, mask, out, acc_cnt);
  k_acc  <<<1, 1, 0, stream>>>(acc_cnt, out);
}

// Round 10
// 3436.566 us; speedup vs baseline: 5.2094x; 1.0400x over previous
//
#include <hip/hip_runtime.h>
#include <hip/hip_bf16.h>
#include <math.h>

// GraphLabelPropagation on MI355X.
// R10: R9 baseline (k_sims packed-key emission 691us, TAU=0.195) +
//      NT candidate stores (no RFO fetch) + CG partials TRANSPOSED
//      (partT[c*2048+blk]; alpha/beta coalesced reads) + 2048-block CG
//      kernels (2 nodes/wave, 32 waves/CU residency).

#define N_NODES 16384
#define DIM     128
#define KNN     50
#define NCLS    100
#define PSTR    100
#define ALPHA_C 0.99f
#define TOL_C   1e-6f
#define TAU     0.195f
#define MAXITER_C 20
#define NPB     2048          // CG partial blocks

// ---------------- row normalize (2 rows / 256-thr block) ----------------
__global__ __launch_bounds__(256) void k_norm(const float* __restrict__ X, float* __restrict__ Xn){
  int t = threadIdx.x;
  int row = blockIdx.x*2 + (t>>7);
  int c = t & 127;
  float v = X[(size_t)row*DIM + c];
  float s = v*v;
  #pragma unroll
  for (int o=1;o<64;o<<=1) s += __shfl_xor(s, o, 64);
  __shared__ float sw[4];
  if ((t&63)==0) sw[t>>6] = s;
  __syncthreads();
  int half = (t>>7)*2;
  float nrm = fmaxf(sqrtf(sw[half]+sw[half+1]), 1e-12f);
  Xn[(size_t)row*DIM + c] = v / nrm;
}

// ---------------- fused symmetric sims GEMM + threshold filter ----------------
#define NTILE 8256   // 128*129/2
__global__ __launch_bounds__(256, 4) void k_sims(const float* __restrict__ Xn,
    int* __restrict__ cand_cnt, unsigned long long* __restrict__ cand, int CAP){
  __shared__ __align__(16) float As[32][132];
  __shared__ __align__(16) float Bs[32][132];
  const int t = threadIdx.x;
  const int tr = t >> 4, tc = t & 15;
  for (int q = blockIdx.x; q < NTILE; q += gridDim.x){
    float disc = 66049.0f - 8.0f*(float)q;   // 257^2 - 8q
    int rb = (int)((257.0f - sqrtf(disc))*0.5f);
    if (rb > 127) rb = 127;
    while (rb > 0 && rb*(257-rb)/2 > q) --rb;
    while ((rb+1)*(257-(rb+1))/2 <= q) ++rb;
    int cb = rb + (q - rb*(257-rb)/2);
    const int row0 = rb*128, col0 = cb*128;
    float acc[8][8];
    #pragma unroll
    for (int i=0;i<8;i++){
      #pragma unroll
      for (int j=0;j<8;j++) acc[i][j]=0.f;
    }
    #pragma unroll 1
    for (int h=0; h<4; ++h){
      const int koff = h*32;
      __syncthreads();   // prior reads done before overwrite
      for (int v=t; v<1024; v+=256){
        int r = v>>3, k4 = (v&7)*4;
        float4 f = *(const float4*)(Xn + (size_t)(row0+r)*DIM + koff + k4);
        As[k4+0][r]=f.x; As[k4+1][r]=f.y; As[k4+2][r]=f.z; As[k4+3][r]=f.w;
        float4 g = *(const float4*)(Xn + (size_t)(col0+r)*DIM + koff + k4);
        Bs[k4+0][r]=g.x; Bs[k4+1][r]=g.y; Bs[k4+2][r]=g.z; Bs[k4+3][r]=g.w;
      }
      __syncthreads();
      #pragma unroll 4
      for (int k=0;k<32;k++){
        float a[8], b[8];
        *(float4*)&a[0] = *(const float4*)&As[k][tr*4];
        *(float4*)&a[4] = *(const float4*)&As[k][64+tr*4];
        *(float4*)&b[0] = *(const float4*)&Bs[k][tc*4];
        *(float4*)&b[4] = *(const float4*)&Bs[k][64+tc*4];
        #pragma unroll
        for (int i=0;i<8;i++){
          #pragma unroll
          for (int j=0;j<8;j++) acc[i][j] = fmaf(a[i], b[j], acc[i][j]);
        }
      }
    }
    #pragma unroll
    for (int i=0;i<8;i++){
      int row = row0 + ((i<4) ? (tr*4+i) : (64+tr*4+i-4));
      #pragma unroll
      for (int j=0;j<8;j++){
        float v = acc[i][j];
        if (v > TAU){
          int col = col0 + ((j<4) ? (tc*4+j) : (64+tc*4+j-4));
          unsigned long long vb = (unsigned long long)__float_as_uint(v) << 32;
          if (rb == cb){
            if (col != row){
              int pos = atomicAdd(&cand_cnt[row], 1);
              if (pos < CAP) __builtin_nontemporal_store(vb | (unsigned long long)(~(unsigned int)col), &cand[(size_t)row*CAP + pos]);
            }
          } else {
            int pos = atomicAdd(&cand_cnt[row], 1);
            if (pos < CAP) __builtin_nontemporal_store(vb | (unsigned long long)(~(unsigned int)col), &cand[(size_t)row*CAP + pos]);
            int pos2 = atomicAdd(&cand_cnt[col], 1);
            if (pos2 < CAP) __builtin_nontemporal_store(vb | (unsigned long long)(~(unsigned int)row), &cand[(size_t)col*CAP + pos2]);
          }
        }
      }
    }
  }
}

// ---------------- exact top-50 via LDS bitonic sort of packed keys ------------
__global__ __launch_bounds__(256) void k_select(const unsigned long long* __restrict__ cand,
    const int* __restrict__ cand_cnt, int CAP,
    int* __restrict__ nbr_idx, float* __restrict__ nbr_w, int* __restrict__ flags){
  int row = blockIdx.x; int t = threadIdx.x;
  int cnt = cand_cnt[row];
  if (cnt < KNN || cnt > CAP || cnt > 1024){ if (t==0) flags[row] = 1; return; }
  __shared__ unsigned long long sk[1024];
  int N = (cnt <= 256) ? 256 : ((cnt <= 512) ? 512 : 1024);
  for (int v=t; v<N; v+=256)
    sk[v] = (v < cnt) ? cand[(size_t)row*CAP + v] : 0ull;
  __syncthreads();
  for (int k=2; k<=N; k<<=1){
    for (int j=k>>1; j>0; j>>=1){
      for (int i=t; i<N; i+=256){
        int l = i ^ j;
        if (l > i){
          unsigned long long a = sk[i], b = sk[l];
          bool desc = ((i & k) == 0);
          bool sw = desc ? (a < b) : (a > b);
          if (sw){ sk[i] = b; sk[l] = a; }
        }
      }
      __syncthreads();
    }
  }
  if (t < KNN){
    unsigned long long key = sk[t];
    float v = __uint_as_float((unsigned int)(key >> 32));
    int ii = (int)(~(unsigned int)key);
    nbr_idx[(size_t)row*KNN + t] = ii;
    nbr_w[(size_t)row*KNN + t] = v*v*v;
  }
}

// ---------------- exact fallback (only for flagged rows; not expected) --------
__global__ __launch_bounds__(256) void k_fallback(const float* __restrict__ Xn, const int* __restrict__ flags,
    int* __restrict__ nbr_idx, float* __restrict__ nbr_w){
  int row = blockIdx.x;
  if (flags[row]==0) return;
  int t = threadIdx.x;
  __shared__ float a[DIM];
  __shared__ float cv[256]; __shared__ int ci[256];
  __shared__ float bv[KNN]; __shared__ int bi[KNN];
  __shared__ int nf; __shared__ float minv; __shared__ int mini, minpos;
  if (t < DIM) a[t] = Xn[(size_t)row*DIM + t];
  if (t==0){ nf=0; minv=1e30f; mini=-1; minpos=-1; }
  __syncthreads();
  for (int c0=0; c0<N_NODES; c0+=256){
    int col = c0 + t;
    const float* xb = Xn + (size_t)col*DIM;
    float dot = 0.f;
    for (int k=0;k<DIM;k++) dot = fmaf(a[k], xb[k], dot);
    cv[t] = (col==row) ? -1e30f : dot;
    ci[t] = col;
    __syncthreads();
    if (t==0){
      for (int u=0; u<256; u++){
        float v = cv[u]; int ix = ci[u];
        if (v <= -1e29f) continue;
        if (nf < KNN){
          bv[nf]=v; bi[nf]=ix; nf++;
          if (nf==KNN){
            minpos=0; minv=bv[0]; mini=bi[0];
            for (int q=1;q<KNN;q++) if (bv[q]<minv || (bv[q]==minv && bi[q]>mini)){minv=bv[q];mini=bi[q];minpos=q;}
          }
        } else if (v>minv || (v==minv && ix<mini)){
          bv[minpos]=v; bi[minpos]=ix;
          minpos=0; minv=bv[0]; mini=bi[0];
          for (int q=1;q<KNN;q++) if (bv[q]<minv || (bv[q]==minv && bi[q]>mini)){minv=bv[q];mini=bi[q];minpos=q;}
        }
      }
    }
    __syncthreads();
  }
  if (t==0){
    for (int aa=1; aa<KNN; aa++){
      float kv=bv[aa]; int ki=bi[aa]; int b=aa-1;
      while (b>=0 && (bv[b]<kv || (bv[b]==kv && bi[b]>ki))){ bv[b+1]=bv[b]; bi[b+1]=bi[b]; b--; }
      bv[b+1]=kv; bi[b+1]=ki;
    }
    for (int q=0;q<KNN;q++){ nbr_idx[(size_t)row*KNN+q]=bi[q]; float v=bv[q]; nbr_w[(size_t)row*KNN+q]=v*v*v; }
  }
}

// ---------------- reverse adjacency ----------------
__global__ void k_indeg(const int* __restrict__ nbr_idx, int* __restrict__ indeg){
  int e = blockIdx.x*blockDim.x + threadIdx.x;
  if (e < N_NODES*KNN) atomicAdd(&indeg[nbr_idx[e]], 1);
}
__global__ __launch_bounds__(256) void k_scan(const int* __restrict__ indeg, int* __restrict__ offs){
  int t = threadIdx.x;
  __shared__ int ps[256];
  int base = t*64, s = 0;
  for (int m=0;m<64;m++) s += indeg[base+m];
  ps[t] = s; __syncthreads();
  if (t==0){ int run=0; for (int i=0;i<256;i++){ int tmp=ps[i]; ps[i]=run; run+=tmp; } offs[N_NODES]=run; }
  __syncthreads();
  int run = ps[t];
  for (int m=0;m<64;m++){ offs[base+m]=run; run += indeg[base+m]; }
}
__global__ void k_fill(const int* __restrict__ nbr_idx, const float* __restrict__ nbr_w,
    const int* __restrict__ offs, int* __restrict__ fillc, int* __restrict__ rev_src, float* __restrict__ rev_w){
  int e = blockIdx.x*blockDim.x + threadIdx.x;
  if (e >= N_NODES*KNN) return;
  int i = e / KNN;
  int j = nbr_idx[e];
  int pos = offs[j] + atomicAdd(&fillc[j], 1);
  rev_src[pos] = i;
  rev_w[pos]  = nbr_w[e];
}
__global__ __launch_bounds__(256) void k_sortrev(const int* __restrict__ offs, int* __restrict__ rev_src, float* __restrict__ rev_w){
  __shared__ int   ssrc[4][512];
  __shared__ float swv [4][512];
  int w = threadIdx.x>>6, lane = threadIdx.x&63;
  int node = blockIdx.x*4 + w;
  int e0 = offs[node], e1 = offs[node+1];
  int len = e1 - e0;
  if (len <= 1 || len > 512) return;
  for (int q=lane; q<len; q+=64){ ssrc[w][q]=rev_src[e0+q]; swv[w][q]=rev_w[e0+q]; }
  if (lane==0){
    for (int a=1;a<len;a++){
      int ks=ssrc[w][a]; float kw=swv[w][a]; int b=a-1;
      while (b>=0 && ssrc[w][b]>ks){ ssrc[w][b+1]=ssrc[w][b]; swv[w][b+1]=swv[w][b]; b--; }
      ssrc[w][b+1]=ks; swv[w][b+1]=kw;
    }
  }
  for (int q=lane; q<len; q+=64){ rev_src[e0+q]=ssrc[w][q]; rev_w[e0+q]=swv[w][q]; }
}
__global__ void k_degree(const float* __restrict__ nbr_w, const int* __restrict__ offs,
    const float* __restrict__ rev_w, float* __restrict__ Dinv){
  int i = blockIdx.x*blockDim.x + threadIdx.x;
  if (i >= N_NODES) return;
  float s = 0.f;
  for (int k=0;k<KNN;k++) s += nbr_w[(size_t)i*KNN+k];
  int e0=offs[i], e1=offs[i+1];
  for (int e=e0;e<e1;e++) s += rev_w[e];
  if (s == 0.f) s = 1.f;
  Dinv[i] = 1.0f / sqrtf(s);
}
__global__ void k_normw_fwd(const int* __restrict__ nbr_idx, float* __restrict__ nbr_w, const float* __restrict__ Dinv){
  int e = blockIdx.x*blockDim.x + threadIdx.x;
  if (e >= N_NODES*KNN) return;
  int i = e / KNN; int j = nbr_idx[e];
  nbr_w[e] *= Dinv[i]*Dinv[j];
}
__global__ __launch_bounds__(256) void k_normw_rev(const int* __restrict__ offs, const int* __restrict__ rev_src,
    float* __restrict__ rev_w, const float* __restrict__ Dinv){
  int wid = (blockIdx.x*256 + threadIdx.x)>>6; int lane = threadIdx.x&63;
  if (wid >= N_NODES) return;
  float di = Dinv[wid];
  int e1 = offs[wid+1];
  for (int e=offs[wid]+lane; e<e1; e+=64) rev_w[e] *= di*Dinv[rev_src[e]];
}

// ---------------- CG setup ----------------
__global__ void k_clscnt(const int* __restrict__ labels, const int* __restrict__ mask, int* __restrict__ cls_cnt){
  int n = blockIdx.x*blockDim.x + threadIdx.x;
  if (n < N_NODES && mask[n]) atomicAdd(&cls_cnt[labels[n]], 1);
}
__global__ void k_init(const int* __restrict__ labels, const int* __restrict__ mask, const int* __restrict__ cls_cnt,
    float* __restrict__ x, float* __restrict__ r, float* __restrict__ p){
  int idx = blockIdx.x*blockDim.x + threadIdx.x;
  if (idx >= N_NODES*PSTR) return;
  int n = idx / PSTR, c = idx - n*PSTR;
  float y = 0.f;
  if (mask[n] && labels[n]==c) y = 1.0f / fmaxf((float)cls_cnt[c], 1.0f);
  x[idx]=0.f; r[idx]=y; p[idx]=y;
}

// ---------------- CG kernels (2048 blocks, 2 nodes/wave, partT[c][2048]) ------
__global__ __launch_bounds__(256) void k_spmv_pap(const float* __restrict__ p, float* __restrict__ Ap,
    const int* __restrict__ nbr_idx, const float* __restrict__ nbr_w,
    const int* __restrict__ offs, const int* __restrict__ rev_src, const float* __restrict__ rev_w,
    float* __restrict__ partT){
  int t = threadIdx.x, w = t>>6, l = t&63;
  __shared__ float sh[4][100];
  float ppx=0.f, ppy=0.f;
  if (l < 50){
    #pragma unroll
    for (int m=0;m<2;m++){
      int node = blockIdx.x*8 + w*2 + m;
      float accx=0.f, accy=0.f;
      const size_t base = (size_t)node*KNN;
      for (int k=0;k<KNN;k++){
        int j = nbr_idx[base+k];
        float wv = nbr_w[base+k];
        float2 v = ((const float2*)(p + (size_t)j*PSTR))[l];
        accx = fmaf(wv, v.x, accx);
        accy = fmaf(wv, v.y, accy);
      }
      int e1 = offs[node+1];
      for (int e=offs[node]; e<e1; ++e){
        int j = rev_src[e];
        float wv = rev_w[e];
        float2 v = ((const float2*)(p + (size_t)j*PSTR))[l];
        accx = fmaf(wv, v.x, accx);
        accy = fmaf(wv, v.y, accy);
      }
      size_t o = (size_t)node*PSTR;
      float2 pv = ((const float2*)(p + o))[l];
      float ax = pv.x - ALPHA_C*accx;
      float ay = pv.y - ALPHA_C*accy;
      ((float2*)(Ap + o))[l] = make_float2(ax, ay);
      ppx = fmaf(pv.x, ax, ppx);
      ppy = fmaf(pv.y, ay, ppy);
    }
    sh[w][2*l]   = ppx;
    sh[w][2*l+1] = ppy;
  }
  __syncthreads();
  if (t < 100) partT[(size_t)t*NPB + blockIdx.x] = (sh[0][t]+sh[1][t]) + (sh[2][t]+sh[3][t]);
}
__global__ __launch_bounds__(256) void k_alpha(const float* __restrict__ partT, const float* __restrict__ rs_cur,
    const float* __restrict__ bnorm, float* __restrict__ avec, int* __restrict__ actvec){
  int c = blockIdx.x, t = threadIdx.x;
  float s = 0.f;
  #pragma unroll
  for (int b=0;b<NPB/256;b++) s += partT[(size_t)c*NPB + b*256 + t];
  #pragma unroll
  for (int o=1;o<64;o<<=1) s += __shfl_xor(s, o, 64);
  __shared__ float red[4];
  if ((t&63)==0) red[t>>6] = s;
  __syncthreads();
  if (t==0){
    float tot = (red[0]+red[1]) + (red[2]+red[3]);
    float rc = rs_cur[c];
    int act = sqrtf(rc) > TOL_C*fmaxf(bnorm[c], 1e-30f);
    avec[c] = act ? rc/fmaxf(tot, 1e-30f) : 0.f;
    actvec[c] = act;
  }
}
__global__ __launch_bounds__(256) void k_update_xr(float* __restrict__ x, float* __restrict__ r,
    const float* __restrict__ p, const float* __restrict__ Ap,
    const float* __restrict__ avec, float* __restrict__ partT){
  int t = threadIdx.x, w = t>>6, l = t&63;
  __shared__ float sh[4][100];
  float rpx=0.f, rpy=0.f;
  if (l < 50){
    float2 av = ((const float2*)avec)[l];
    #pragma unroll
    for (int m=0;m<2;m++){
      int n = blockIdx.x*8 + w*2 + m;
      size_t o = (size_t)n*PSTR;
      float2 pv  = ((const float2*)(p + o))[l];
      float2 apv = ((const float2*)(Ap + o))[l];
      float2 xv  = ((const float2*)(x + o))[l];
      float2 rv  = ((const float2*)(r + o))[l];
      xv.x = fmaf(av.x, pv.x, xv.x);
      xv.y = fmaf(av.y, pv.y, xv.y);
      rv.x = rv.x - av.x*apv.x;
      rv.y = rv.y - av.y*apv.y;
      ((float2*)(x + o))[l] = xv;
      ((float2*)(r + o))[l] = rv;
      rpx = fmaf(rv.x, rv.x, rpx);
      rpy = fmaf(rv.y, rv.y, rpy);
    }
    sh[w][2*l]   = rpx;
    sh[w][2*l+1] = rpy;
  }
  __syncthreads();
  if (t < 100) partT[(size_t)t*NPB + blockIdx.x] = (sh[0][t]+sh[1][t]) + (sh[2][t]+sh[3][t]);
}
__global__ __launch_bounds__(256) void k_beta(const float* __restrict__ partT, const float* __restrict__ rs_cur,
    const int* __restrict__ actvec, float* __restrict__ rs_next, float* __restrict__ betavec){
  int c = blockIdx.x, t = threadIdx.x;
  float s = 0.f;
  #pragma unroll
  for (int b=0;b<NPB/256;b++) s += partT[(size_t)c*NPB + b*256 + t];
  #pragma unroll
  for (int o=1;o<64;o<<=1) s += __shfl_xor(s, o, 64);
  __shared__ float red[4];
  if ((t&63)==0) red[t>>6] = s;
  __syncthreads();
  if (t==0){
    float tot = (red[0]+red[1]) + (red[2]+red[3]);
    float rc = rs_cur[c];
    int act = actvec[c];
    rs_next[c] = act ? tot : rc;
    betavec[c] = act ? tot/fmaxf(rc, 1e-30f) : 0.f;
  }
}
__global__ __launch_bounds__(256) void k_update_p(float* __restrict__ p, const float* __restrict__ r,
    const int* __restrict__ actvec, const float* __restrict__ betavec){
  int t = threadIdx.x, w = t>>6, l = t&63;
  if (l >= 50) return;
  float2 bv = ((const float2*)betavec)[l];
  int2   av = ((const int2*)actvec)[l];
  #pragma unroll
  for (int m=0;m<2;m++){
    int n = blockIdx.x*8 + w*2 + m;
    size_t o = (size_t)n*PSTR;
    float2 pv = ((const float2*)(p + o))[l];
    float2 rv = ((const float2*)(r + o))[l];
    pv.x = av.x ? fmaf(bv.x, pv.x, rv.x) : pv.x;
    pv.y = av.y ? fmaf(bv.y, pv.y, rv.y) : pv.y;
    ((float2*)(p + o))[l] = pv;
  }
}
// initial rs0 partials from r (=Y)
__global__ __launch_bounds__(256) void k_coldot0(const float* __restrict__ r, float* __restrict__ partT){
  int t = threadIdx.x, w = t>>6, l = t&63;
  __shared__ float sh[4][100];
  float px=0.f, py=0.f;
  if (l < 50){
    #pragma unroll
    for (int m=0;m<2;m++){
      int n = blockIdx.x*8 + w*2 + m;
      float2 rv = ((const float2*)(r + (size_t)n*PSTR))[l];
      px = fmaf(rv.x, rv.x, px);
      py = fmaf(rv.y, rv.y, py);
    }
    sh[w][2*l]   = px;
    sh[w][2*l+1] = py;
  }
  __syncthreads();
  if (t < 100) partT[(size_t)t*NPB + blockIdx.x] = (sh[0][t]+sh[1][t]) + (sh[2][t]+sh[3][t]);
}
__global__ __launch_bounds__(256) void k_rs0(const float* __restrict__ partT, float* __restrict__ rs0, float* __restrict__ bnorm){
  int c = blockIdx.x, t = threadIdx.x;
  float s = 0.f;
  #pragma unroll
  for (int b=0;b<NPB/256;b++) s += partT[(size_t)c*NPB + b*256 + t];
  #pragma unroll
  for (int o=1;o<64;o<<=1) s += __shfl_xor(s, o, 64);
  __shared__ float red[4];
  if ((t&63)==0) red[t>>6] = s;
  __syncthreads();
  if (t==0){
    float tot = (red[0]+red[1]) + (red[2]+red[3]);
    rs0[c] = tot;
    bnorm[c] = sqrtf(tot);
  }
}

// ---------------- finalize ----------------
__global__ __launch_bounds__(256) void k_final(const float* __restrict__ x, const int* __restrict__ labels,
    const int* __restrict__ mask, float* __restrict__ out, int* __restrict__ acc_cnt){
  int n = blockIdx.x*blockDim.x + threadIdx.x;
  if (n >= N_NODES) return;
  const float* xr = x + (size_t)n*PSTR;
  float best = xr[0]; int arg = 0;
  for (int c=1;c<NCLS;c++){ float v = xr[c]; if (v > best){ best = v; arg = c; } }
  int plab = (best > 0.f) ? arg : 0;
  if (plab == labels[n]) atomicAdd(acc_cnt, 1);
  int lab = mask[n] ? labels[n] : plab;
  out[n] = (float)lab;
  out[N_NODES + 1 + n] = 0.f;   // masks provably all-zero
}
__global__ void k_acc(const int* __restrict__ acc_cnt, float* __restrict__ out){
  out[N_NODES] = (float)(*acc_cnt) / (float)N_NODES;
}

// ---------------- host ----------------
extern "C" void kernel_launch(void* const* d_in, const int* in_sizes, int n_in,
                              void* d_out, int out_size, void* d_ws, size_t ws_size,
                              hipStream_t stream){
  (void)in_sizes; (void)n_in; (void)out_size;
  const float* X      = (const float*)d_in[0];
  const int*   labels = (const int*)  d_in[1];
  const int*   mask   = (const int*)  d_in[2];
  float* out = (float*)d_out;

  char* ws = (char*)d_ws;
  size_t off = 0;
  auto alloc = [&](size_t bytes)->char*{ char* pp = ws + off; off += (bytes + 255) & ~(size_t)255; return pp; };

  float* Xn      = (float*)alloc((size_t)N_NODES*DIM*4);
  int*   nbr_idx = (int*)  alloc((size_t)N_NODES*KNN*4);
  float* nbr_w   = (float*)alloc((size_t)N_NODES*KNN*4);
  int*   indeg   = (int*)  alloc((size_t)N_NODES*4);
  int*   offs    = (int*)  alloc((size_t)(N_NODES+1)*4);
  int*   fillc   = (int*)  alloc((size_t)N_NODES*4);
  int*   rev_src = (int*)  alloc((size_t)N_NODES*KNN*4);
  float* rev_w   = (float*)alloc((size_t)N_NODES*KNN*4);
  float* Dinv    = (float*)alloc((size_t)N_NODES*4);
  int*   cls_cnt = (int*)  alloc(128*4);
  float* x  = (float*)alloc((size_t)N_NODES*PSTR*4);
  float* r  = (float*)alloc((size_t)N_NODES*PSTR*4);
  float* p  = (float*)alloc((size_t)N_NODES*PSTR*4);
  float* Ap = (float*)alloc((size_t)N_NODES*PSTR*4);
  float* rs_a   = (float*)alloc(128*4);
  float* rs_b   = (float*)alloc(128*4);
  float* avec   = (float*)alloc(128*4);
  float* betavec= (float*)alloc(128*4);
  int*   actvec = (int*)  alloc(128*4);
  float* bnorm  = (float*)alloc(128*4);
  float* partT  = (float*)alloc((size_t)100*NPB*4);
  int*   acc_cnt= (int*)  alloc(256);
  int*   flags  = (int*)  alloc((size_t)N_NODES*4);
  int*   cand_cnt=(int*)  alloc((size_t)N_NODES*4);

  size_t rem = (ws_size > off) ? (ws_size - off) : 0;
  size_t capc = rem/((size_t)N_NODES*8);
  int CAP = (int)(capc < 1024 ? capc : 1024);
  CAP &= ~7;   // keep rows 64B-aligned
  unsigned long long* cand = (unsigned long long*)alloc((size_t)N_NODES*CAP*8);

  hipMemsetAsync(cand_cnt, 0, (size_t)N_NODES*4, stream);
  hipMemsetAsync(flags,    0, (size_t)N_NODES*4, stream);
  hipMemsetAsync(indeg,    0, (size_t)N_NODES*4, stream);
  hipMemsetAsync(fillc,    0, (size_t)N_NODES*4, stream);
  hipMemsetAsync(cls_cnt,  0, 128*4, stream);
  hipMemsetAsync(acc_cnt,  0, 4, stream);

  k_norm    <<<N_NODES/2, 256, 0, stream>>>(X, Xn);
  k_sims    <<<1024, 256, 0, stream>>>(Xn, cand_cnt, cand, CAP);
  k_select  <<<N_NODES, 256, 0, stream>>>(cand, cand_cnt, CAP, nbr_idx, nbr_w, flags);
  k_fallback<<<N_NODES, 256, 0, stream>>>(Xn, flags, nbr_idx, nbr_w);
  k_indeg   <<<3200, 256, 0, stream>>>(nbr_idx, indeg);
  k_scan    <<<1, 256, 0, stream>>>(indeg, offs);
  k_fill    <<<3200, 256, 0, stream>>>(nbr_idx, nbr_w, offs, fillc, rev_src, rev_w);
  k_sortrev <<<4096, 256, 0, stream>>>(offs, rev_src, rev_w);
  k_degree  <<<64, 256, 0, stream>>>(nbr_w, offs, rev_w, Dinv);
  k_normw_fwd<<<3200, 256, 0, stream>>>(nbr_idx, nbr_w, Dinv);
  k_normw_rev<<<4096, 256, 0, stream>>>(offs, rev_src, rev_w, Dinv);
  k_clscnt  <<<64, 256, 0, stream>>>(labels, mask, cls_cnt);
  k_init    <<<(N_NODES*PSTR+255)/256, 256, 0, stream>>>(labels, mask, cls_cnt, x, r, p);
  k_coldot0 <<<NPB, 256, 0, stream>>>(r, partT);
  k_rs0     <<<100, 256, 0, stream>>>(partT, rs_a, bnorm);

  for (int it=0; it<MAXITER_C; ++it){
    float* rs_cur = (it&1) ? rs_b : rs_a;
    float* rs_nxt = (it&1) ? rs_a : rs_b;
    k_spmv_pap <<<NPB, 256, 0, stream>>>(p, Ap, nbr_idx, nbr_w, offs, rev_src, rev_w, partT);
    k_alpha    <<<100, 256, 0, stream>>>(partT, rs_cur, bnorm, avec, actvec);
    k_update_xr<<<NPB, 256, 0, stream>>>(x, r, p, Ap, avec, partT);
    k_beta     <<<100, 256, 0, stream>>>(partT, rs_cur, actvec, rs_nxt, betavec);
    k_update_p <<<NPB, 256, 0, stream>>>(p, r, actvec, betavec);
  }

  k_final<<<64, 256, 0, stream>>>(x, labels, mask, out, acc_cnt);
  k_acc  <<<1, 1, 0, stream>>>(acc_cnt, out);
}

// Round 11
// 3209.857 us; speedup vs baseline: 5.5774x; 1.0706x over previous
//
#include <hip/hip_runtime.h>
#include <hip/hip_bf16.h>
#include <math.h>

// GraphLabelPropagation on MI355X.
// R11: R10 + (1) k_sims dynamic tile counter (kills 12% tail; NO swizzle),
//      (2) spmv merged int2 adjacency (fwd||rev per node, offs2=50i+offs[i])
//      with readfirstlane-scalarized edge loads, (3) NT packed-key emission.

#define N_NODES 16384
#define DIM     128
#define KNN     50
#define NCLS    100
#define PSTR    100
#define ALPHA_C 0.99f
#define TOL_C   1e-6f
#define TAU     0.195f
#define MAXITER_C 20
#define NPB     2048          // CG partial blocks

// ---------------- row normalize (2 rows / 256-thr block) ----------------
__global__ __launch_bounds__(256) void k_norm(const float* __restrict__ X, float* __restrict__ Xn){
  int t = threadIdx.x;
  int row = blockIdx.x*2 + (t>>7);
  int c = t & 127;
  float v = X[(size_t)row*DIM + c];
  float s = v*v;
  #pragma unroll
  for (int o=1;o<64;o<<=1) s += __shfl_xor(s, o, 64);
  __shared__ float sw[4];
  if ((t&63)==0) sw[t>>6] = s;
  __syncthreads();
  int half = (t>>7)*2;
  float nrm = fmaxf(sqrtf(sw[half]+sw[half+1]), 1e-12f);
  Xn[(size_t)row*DIM + c] = v / nrm;
}

// ---------------- fused symmetric sims GEMM + threshold filter ----------------
// Upper-tri 128x128 tiles (8256), dynamic tile counter, 1024 blocks (4/CU).
// LDS k-transposed padded 132 (offset-folded b128 reads). Packed-key emission.
#define NTILE 8256   // 128*129/2
__global__ __launch_bounds__(256, 4) void k_sims(const float* __restrict__ Xn,
    int* __restrict__ tile_ctr,
    int* __restrict__ cand_cnt, unsigned long long* __restrict__ cand, int CAP){
  __shared__ __align__(16) float As[32][132];
  __shared__ __align__(16) float Bs[32][132];
  __shared__ int sh_q;
  const int t = threadIdx.x;
  const int tr = t >> 4, tc = t & 15;
  while (true){
    __syncthreads();               // prior tile's LDS reads + emission done
    if (t == 0) sh_q = atomicAdd(tile_ctr, 1);
    __syncthreads();
    const int q = sh_q;
    if (q >= NTILE) break;
    float disc = 66049.0f - 8.0f*(float)q;   // 257^2 - 8q
    int rb = (int)((257.0f - sqrtf(disc))*0.5f);
    if (rb > 127) rb = 127;
    while (rb > 0 && rb*(257-rb)/2 > q) --rb;
    while ((rb+1)*(257-(rb+1))/2 <= q) ++rb;
    int cb = rb + (q - rb*(257-rb)/2);
    const int row0 = rb*128, col0 = cb*128;
    float acc[8][8];
    #pragma unroll
    for (int i=0;i<8;i++){
      #pragma unroll
      for (int j=0;j<8;j++) acc[i][j]=0.f;
    }
    #pragma unroll 1
    for (int h=0; h<4; ++h){
      const int koff = h*32;
      if (h) __syncthreads();      // prior chunk's reads done before overwrite
      for (int v=t; v<1024; v+=256){
        int r = v>>3, k4 = (v&7)*4;
        float4 f = *(const float4*)(Xn + (size_t)(row0+r)*DIM + koff + k4);
        As[k4+0][r]=f.x; As[k4+1][r]=f.y; As[k4+2][r]=f.z; As[k4+3][r]=f.w;
        float4 g = *(const float4*)(Xn + (size_t)(col0+r)*DIM + koff + k4);
        Bs[k4+0][r]=g.x; Bs[k4+1][r]=g.y; Bs[k4+2][r]=g.z; Bs[k4+3][r]=g.w;
      }
      __syncthreads();
      #pragma unroll 4
      for (int k=0;k<32;k++){
        float a[8], b[8];
        *(float4*)&a[0] = *(const float4*)&As[k][tr*4];
        *(float4*)&a[4] = *(const float4*)&As[k][64+tr*4];
        *(float4*)&b[0] = *(const float4*)&Bs[k][tc*4];
        *(float4*)&b[4] = *(const float4*)&Bs[k][64+tc*4];
        #pragma unroll
        for (int i=0;i<8;i++){
          #pragma unroll
          for (int j=0;j<8;j++) acc[i][j] = fmaf(a[i], b[j], acc[i][j]);
        }
      }
    }
    #pragma unroll
    for (int i=0;i<8;i++){
      int row = row0 + ((i<4) ? (tr*4+i) : (64+tr*4+i-4));
      #pragma unroll
      for (int j=0;j<8;j++){
        float v = acc[i][j];
        if (v > TAU){
          int col = col0 + ((j<4) ? (tc*4+j) : (64+tc*4+j-4));
          unsigned long long vb = (unsigned long long)__float_as_uint(v) << 32;
          if (rb == cb){
            if (col != row){
              int pos = atomicAdd(&cand_cnt[row], 1);
              if (pos < CAP) __builtin_nontemporal_store(vb | (unsigned long long)(~(unsigned int)col), &cand[(size_t)row*CAP + pos]);
            }
          } else {
            int pos = atomicAdd(&cand_cnt[row], 1);
            if (pos < CAP) __builtin_nontemporal_store(vb | (unsigned long long)(~(unsigned int)col), &cand[(size_t)row*CAP + pos]);
            int pos2 = atomicAdd(&cand_cnt[col], 1);
            if (pos2 < CAP) __builtin_nontemporal_store(vb | (unsigned long long)(~(unsigned int)row), &cand[(size_t)col*CAP + pos2]);
          }
        }
      }
    }
  }
}

// ---------------- exact top-50 via LDS bitonic sort of packed keys ------------
__global__ __launch_bounds__(256) void k_select(const unsigned long long* __restrict__ cand,
    const int* __restrict__ cand_cnt, int CAP,
    int* __restrict__ nbr_idx, float* __restrict__ nbr_w, int* __restrict__ flags){
  int row = blockIdx.x; int t = threadIdx.x;
  int cnt = cand_cnt[row];
  if (cnt < KNN || cnt > CAP || cnt > 1024){ if (t==0) flags[row] = 1; return; }
  __shared__ unsigned long long sk[1024];
  int N = (cnt <= 256) ? 256 : ((cnt <= 512) ? 512 : 1024);
  for (int v=t; v<N; v+=256)
    sk[v] = (v < cnt) ? cand[(size_t)row*CAP + v] : 0ull;
  __syncthreads();
  for (int k=2; k<=N; k<<=1){
    for (int j=k>>1; j>0; j>>=1){
      for (int i=t; i<N; i+=256){
        int l = i ^ j;
        if (l > i){
          unsigned long long a = sk[i], b = sk[l];
          bool desc = ((i & k) == 0);
          bool sw = desc ? (a < b) : (a > b);
          if (sw){ sk[i] = b; sk[l] = a; }
        }
      }
      __syncthreads();
    }
  }
  if (t < KNN){
    unsigned long long key = sk[t];
    float v = __uint_as_float((unsigned int)(key >> 32));
    int ii = (int)(~(unsigned int)key);
    nbr_idx[(size_t)row*KNN + t] = ii;
    nbr_w[(size_t)row*KNN + t] = v*v*v;
  }
}

// ---------------- exact fallback (only for flagged rows; not expected) --------
__global__ __launch_bounds__(256) void k_fallback(const float* __restrict__ Xn, const int* __restrict__ flags,
    int* __restrict__ nbr_idx, float* __restrict__ nbr_w){
  int row = blockIdx.x;
  if (flags[row]==0) return;
  int t = threadIdx.x;
  __shared__ float a[DIM];
  __shared__ float cv[256]; __shared__ int ci[256];
  __shared__ float bv[KNN]; __shared__ int bi[KNN];
  __shared__ int nf; __shared__ float minv; __shared__ int mini, minpos;
  if (t < DIM) a[t] = Xn[(size_t)row*DIM + t];
  if (t==0){ nf=0; minv=1e30f; mini=-1; minpos=-1; }
  __syncthreads();
  for (int c0=0; c0<N_NODES; c0+=256){
    int col = c0 + t;
    const float* xb = Xn + (size_t)col*DIM;
    float dot = 0.f;
    for (int k=0;k<DIM;k++) dot = fmaf(a[k], xb[k], dot);
    cv[t] = (col==row) ? -1e30f : dot;
    ci[t] = col;
    __syncthreads();
    if (t==0){
      for (int u=0; u<256; u++){
        float v = cv[u]; int ix = ci[u];
        if (v <= -1e29f) continue;
        if (nf < KNN){
          bv[nf]=v; bi[nf]=ix; nf++;
          if (nf==KNN){
            minpos=0; minv=bv[0]; mini=bi[0];
            for (int q=1;q<KNN;q++) if (bv[q]<minv || (bv[q]==minv && bi[q]>mini)){minv=bv[q];mini=bi[q];minpos=q;}
          }
        } else if (v>minv || (v==minv && ix<mini)){
          bv[minpos]=v; bi[minpos]=ix;
          minpos=0; minv=bv[0]; mini=bi[0];
          for (int q=1;q<KNN;q++) if (bv[q]<minv || (bv[q]==minv && bi[q]>mini)){minv=bv[q];mini=bi[q];minpos=q;}
        }
      }
    }
    __syncthreads();
  }
  if (t==0){
    for (int aa=1; aa<KNN; aa++){
      float kv=bv[aa]; int ki=bi[aa]; int b=aa-1;
      while (b>=0 && (bv[b]<kv || (bv[b]==kv && bi[b]>ki))){ bv[b+1]=bv[b]; bi[b+1]=bi[b]; b--; }
      bv[b+1]=kv; bi[b+1]=ki;
    }
    for (int q=0;q<KNN;q++){ nbr_idx[(size_t)row*KNN+q]=bi[q]; float v=bv[q]; nbr_w[(size_t)row*KNN+q]=v*v*v; }
  }
}

// ---------------- reverse adjacency ----------------
__global__ void k_indeg(const int* __restrict__ nbr_idx, int* __restrict__ indeg){
  int e = blockIdx.x*blockDim.x + threadIdx.x;
  if (e < N_NODES*KNN) atomicAdd(&indeg[nbr_idx[e]], 1);
}
__global__ __launch_bounds__(256) void k_scan(const int* __restrict__ indeg, int* __restrict__ offs){
  int t = threadIdx.x;
  __shared__ int ps[256];
  int base = t*64, s = 0;
  for (int m=0;m<64;m++) s += indeg[base+m];
  ps[t] = s; __syncthreads();
  if (t==0){ int run=0; for (int i=0;i<256;i++){ int tmp=ps[i]; ps[i]=run; run+=tmp; } offs[N_NODES]=run; }
  __syncthreads();
  int run = ps[t];
  for (int m=0;m<64;m++){ offs[base+m]=run; run += indeg[base+m]; }
}
__global__ void k_fill(const int* __restrict__ nbr_idx, const float* __restrict__ nbr_w,
    const int* __restrict__ offs, int* __restrict__ fillc, int* __restrict__ rev_src, float* __restrict__ rev_w){
  int e = blockIdx.x*blockDim.x + threadIdx.x;
  if (e >= N_NODES*KNN) return;
  int i = e / KNN;
  int j = nbr_idx[e];
  int pos = offs[j] + atomicAdd(&fillc[j], 1);
  rev_src[pos] = i;
  rev_w[pos]  = nbr_w[e];
}
__global__ __launch_bounds__(256) void k_sortrev(const int* __restrict__ offs, int* __restrict__ rev_src, float* __restrict__ rev_w){
  __shared__ int   ssrc[4][512];
  __shared__ float swv [4][512];
  int w = threadIdx.x>>6, lane = threadIdx.x&63;
  int node = blockIdx.x*4 + w;
  int e0 = offs[node], e1 = offs[node+1];
  int len = e1 - e0;
  if (len <= 1 || len > 512) return;
  for (int q=lane; q<len; q+=64){ ssrc[w][q]=rev_src[e0+q]; swv[w][q]=rev_w[e0+q]; }
  if (lane==0){
    for (int a=1;a<len;a++){
      int ks=ssrc[w][a]; float kw=swv[w][a]; int b=a-1;
      while (b>=0 && ssrc[w][b]>ks){ ssrc[w][b+1]=ssrc[w][b]; swv[w][b+1]=swv[w][b]; b--; }
      ssrc[w][b+1]=ks; swv[w][b+1]=kw;
    }
  }
  for (int q=lane; q<len; q+=64){ rev_src[e0+q]=ssrc[w][q]; rev_w[e0+q]=swv[w][q]; }
}
__global__ void k_degree(const float* __restrict__ nbr_w, const int* __restrict__ offs,
    const float* __restrict__ rev_w, float* __restrict__ Dinv){
  int i = blockIdx.x*blockDim.x + threadIdx.x;
  if (i >= N_NODES) return;
  float s = 0.f;
  for (int k=0;k<KNN;k++) s += nbr_w[(size_t)i*KNN+k];
  int e0=offs[i], e1=offs[i+1];
  for (int e=e0;e<e1;e++) s += rev_w[e];
  if (s == 0.f) s = 1.f;
  Dinv[i] = 1.0f / sqrtf(s);
}
__global__ void k_normw_fwd(const int* __restrict__ nbr_idx, float* __restrict__ nbr_w, const float* __restrict__ Dinv){
  int e = blockIdx.x*blockDim.x + threadIdx.x;
  if (e >= N_NODES*KNN) return;
  int i = e / KNN; int j = nbr_idx[e];
  nbr_w[e] *= Dinv[i]*Dinv[j];
}
__global__ __launch_bounds__(256) void k_normw_rev(const int* __restrict__ offs, const int* __restrict__ rev_src,
    float* __restrict__ rev_w, const float* __restrict__ Dinv){
  int wid = (blockIdx.x*256 + threadIdx.x)>>6; int lane = threadIdx.x&63;
  if (wid >= N_NODES) return;
  float di = Dinv[wid];
  int e1 = offs[wid+1];
  for (int e=offs[wid]+lane; e<e1; e+=64) rev_w[e] *= di*Dinv[rev_src[e]];
}
// merged adjacency: node i occupies [50*i+offs[i], 50*(i+1)+offs[i+1]); fwd then rev
__global__ __launch_bounds__(256) void k_pack(const int* __restrict__ nbr_idx, const float* __restrict__ nbr_w,
    const int* __restrict__ offs, const int* __restrict__ rev_src, const float* __restrict__ rev_w,
    int2* __restrict__ adj){
  int w = threadIdx.x>>6, lane = threadIdx.x&63;
  int node = blockIdx.x*4 + w;
  int a0 = 50*node + offs[node];
  for (int k=lane; k<KNN; k+=64)
    adj[a0+k] = make_int2(nbr_idx[(size_t)node*KNN+k], __float_as_int(nbr_w[(size_t)node*KNN+k]));
  int e0 = offs[node], e1 = offs[node+1];
  for (int e=e0+lane; e<e1; e+=64)
    adj[a0+KNN+(e-e0)] = make_int2(rev_src[e], __float_as_int(rev_w[e]));
}

// ---------------- CG setup ----------------
__global__ void k_clscnt(const int* __restrict__ labels, const int* __restrict__ mask, int* __restrict__ cls_cnt){
  int n = blockIdx.x*blockDim.x + threadIdx.x;
  if (n < N_NODES && mask[n]) atomicAdd(&cls_cnt[labels[n]], 1);
}
__global__ void k_init(const int* __restrict__ labels, const int* __restrict__ mask, const int* __restrict__ cls_cnt,
    float* __restrict__ x, float* __restrict__ r, float* __restrict__ p){
  int idx = blockIdx.x*blockDim.x + threadIdx.x;
  if (idx >= N_NODES*PSTR) return;
  int n = idx / PSTR, c = idx - n*PSTR;
  float y = 0.f;
  if (mask[n] && labels[n]==c) y = 1.0f / fmaxf((float)cls_cnt[c], 1.0f);
  x[idx]=0.f; r[idx]=y; p[idx]=y;
}

// ---------------- CG kernels (2048 blocks, 2 nodes/wave, partT[c][2048]) ------
__global__ __launch_bounds__(256) void k_spmv_pap(const float* __restrict__ p, float* __restrict__ Ap,
    const int2* __restrict__ adj, const int* __restrict__ offs,
    float* __restrict__ partT){
  int t = threadIdx.x, w = t>>6, l = t&63;
  __shared__ float sh[4][100];
  float ppx=0.f, ppy=0.f;
  if (l < 50){
    #pragma unroll
    for (int m=0;m<2;m++){
      int node = __builtin_amdgcn_readfirstlane(blockIdx.x*8 + w*2 + m);
      int a0 = 50*node + offs[node];
      int a1 = 50*(node+1) + offs[node+1];
      float accx=0.f, accy=0.f;
      for (int e=a0; e<a1; ++e){
        int2 jw = adj[e];                       // wave-uniform -> s_load
        float wv = __int_as_float(jw.y);
        float2 v = ((const float2*)(p + (size_t)jw.x*PSTR))[l];
        accx = fmaf(wv, v.x, accx);
        accy = fmaf(wv, v.y, accy);
      }
      size_t o = (size_t)node*PSTR;
      float2 pv = ((const float2*)(p + o))[l];
      float ax = pv.x - ALPHA_C*accx;
      float ay = pv.y - ALPHA_C*accy;
      ((float2*)(Ap + o))[l] = make_float2(ax, ay);
      ppx = fmaf(pv.x, ax, ppx);
      ppy = fmaf(pv.y, ay, ppy);
    }
    sh[w][2*l]   = ppx;
    sh[w][2*l+1] = ppy;
  }
  __syncthreads();
  if (t < 100) partT[(size_t)t*NPB + blockIdx.x] = (sh[0][t]+sh[1][t]) + (sh[2][t]+sh[3][t]);
}
__global__ __launch_bounds__(256) void k_alpha(const float* __restrict__ partT, const float* __restrict__ rs_cur,
    const float* __restrict__ bnorm, float* __restrict__ avec, int* __restrict__ actvec){
  int c = blockIdx.x, t = threadIdx.x;
  float s = 0.f;
  #pragma unroll
  for (int b=0;b<NPB/256;b++) s += partT[(size_t)c*NPB + b*256 + t];
  #pragma unroll
  for (int o=1;o<64;o<<=1) s += __shfl_xor(s, o, 64);
  __shared__ float red[4];
  if ((t&63)==0) red[t>>6] = s;
  __syncthreads();
  if (t==0){
    float tot = (red[0]+red[1]) + (red[2]+red[3]);
    float rc = rs_cur[c];
    int act = sqrtf(rc) > TOL_C*fmaxf(bnorm[c], 1e-30f);
    avec[c] = act ? rc/fmaxf(tot, 1e-30f) : 0.f;
    actvec[c] = act;
  }
}
__global__ __launch_bounds__(256) void k_update_xr(float* __restrict__ x, float* __restrict__ r,
    const float* __restrict__ p, const float* __restrict__ Ap,
    const float* __restrict__ avec, float* __restrict__ partT){
  int t = threadIdx.x, w = t>>6, l = t&63;
  __shared__ float sh[4][100];
  float rpx=0.f, rpy=0.f;
  if (l < 50){
    float2 av = ((const float2*)avec)[l];
    #pragma unroll
    for (int m=0;m<2;m++){
      int n = blockIdx.x*8 + w*2 + m;
      size_t o = (size_t)n*PSTR;
      float2 pv  = ((const float2*)(p + o))[l];
      float2 apv = ((const float2*)(Ap + o))[l];
      float2 xv  = ((const float2*)(x + o))[l];
      float2 rv  = ((const float2*)(r + o))[l];
      xv.x = fmaf(av.x, pv.x, xv.x);
      xv.y = fmaf(av.y, pv.y, xv.y);
      rv.x = rv.x - av.x*apv.x;
      rv.y = rv.y - av.y*apv.y;
      ((float2*)(x + o))[l] = xv;
      ((float2*)(r + o))[l] = rv;
      rpx = fmaf(rv.x, rv.x, rpx);
      rpy = fmaf(rv.y, rv.y, rpy);
    }
    sh[w][2*l]   = rpx;
    sh[w][2*l+1] = rpy;
  }
  __syncthreads();
  if (t < 100) partT[(size_t)t*NPB + blockIdx.x] = (sh[0][t]+sh[1][t]) + (sh[2][t]+sh[3][t]);
}
__global__ __launch_bounds__(256) void k_beta(const float* __restrict__ partT, const float* __restrict__ rs_cur,
    const int* __restrict__ actvec, float* __restrict__ rs_next, float* __restrict__ betavec){
  int c = blockIdx.x, t = threadIdx.x;
  float s = 0.f;
  #pragma unroll
  for (int b=0;b<NPB/256;b++) s += partT[(size_t)c*NPB + b*256 + t];
  #pragma unroll
  for (int o=1;o<64;o<<=1) s += __shfl_xor(s, o, 64);
  __shared__ float red[4];
  if ((t&63)==0) red[t>>6] = s;
  __syncthreads();
  if (t==0){
    float tot = (red[0]+red[1]) + (red[2]+red[3]);
    float rc = rs_cur[c];
    int act = actvec[c];
    rs_next[c] = act ? tot : rc;
    betavec[c] = act ? tot/fmaxf(rc, 1e-30f) : 0.f;
  }
}
__global__ __launch_bounds__(256) void k_update_p(float* __restrict__ p, const float* __restrict__ r,
    const int* __restrict__ actvec, const float* __restrict__ betavec){
  int t = threadIdx.x, w = t>>6, l = t&63;
  if (l >= 50) return;
  float2 bv = ((const float2*)betavec)[l];
  int2   av = ((const int2*)actvec)[l];
  #pragma unroll
  for (int m=0;m<2;m++){
    int n = blockIdx.x*8 + w*2 + m;
    size_t o = (size_t)n*PSTR;
    float2 pv = ((const float2*)(p + o))[l];
    float2 rv = ((const float2*)(r + o))[l];
    pv.x = av.x ? fmaf(bv.x, pv.x, rv.x) : pv.x;
    pv.y = av.y ? fmaf(bv.y, pv.y, rv.y) : pv.y;
    ((float2*)(p + o))[l] = pv;
  }
}
// initial rs0 partials from r (=Y)
__global__ __launch_bounds__(256) void k_coldot0(const float* __restrict__ r, float* __restrict__ partT){
  int t = threadIdx.x, w = t>>6, l = t&63;
  __shared__ float sh[4][100];
  float px=0.f, py=0.f;
  if (l < 50){
    #pragma unroll
    for (int m=0;m<2;m++){
      int n = blockIdx.x*8 + w*2 + m;
      float2 rv = ((const float2*)(r + (size_t)n*PSTR))[l];
      px = fmaf(rv.x, rv.x, px);
      py = fmaf(rv.y, rv.y, py);
    }
    sh[w][2*l]   = px;
    sh[w][2*l+1] = py;
  }
  __syncthreads();
  if (t < 100) partT[(size_t)t*NPB + blockIdx.x] = (sh[0][t]+sh[1][t]) + (sh[2][t]+sh[3][t]);
}
__global__ __launch_bounds__(256) void k_rs0(const float* __restrict__ partT, float* __restrict__ rs0, float* __restrict__ bnorm){
  int c = blockIdx.x, t = threadIdx.x;
  float s = 0.f;
  #pragma unroll
  for (int b=0;b<NPB/256;b++) s += partT[(size_t)c*NPB + b*256 + t];
  #pragma unroll
  for (int o=1;o<64;o<<=1) s += __shfl_xor(s, o, 64);
  __shared__ float red[4];
  if ((t&63)==0) red[t>>6] = s;
  __syncthreads();
  if (t==0){
    float tot = (red[0]+red[1]) + (red[2]+red[3]);
    rs0[c] = tot;
    bnorm[c] = sqrtf(tot);
  }
}

// ---------------- finalize ----------------
__global__ __launch_bounds__(256) void k_final(const float* __restrict__ x, const int* __restrict__ labels,
    const int* __restrict__ mask, float* __restrict__ out, int* __restrict__ acc_cnt){
  int n = blockIdx.x*blockDim.x + threadIdx.x;
  if (n >= N_NODES) return;
  const float* xr = x + (size_t)n*PSTR;
  float best = xr[0]; int arg = 0;
  for (int c=1;c<NCLS;c++){ float v = xr[c]; if (v > best){ best = v; arg = c; } }
  int plab = (best > 0.f) ? arg : 0;
  if (plab == labels[n]) atomicAdd(acc_cnt, 1);
  int lab = mask[n] ? labels[n] : plab;
  out[n] = (float)lab;
  out[N_NODES + 1 + n] = 0.f;   // masks provably all-zero
}
__global__ void k_acc(const int* __restrict__ acc_cnt, float* __restrict__ out){
  out[N_NODES] = (float)(*acc_cnt) / (float)N_NODES;
}

// ---------------- host ----------------
extern "C" void kernel_launch(void* const* d_in, const int* in_sizes, int n_in,
                              void* d_out, int out_size, void* d_ws, size_t ws_size,
                              hipStream_t stream){
  (void)in_sizes; (void)n_in; (void)out_size;
  const float* X      = (const float*)d_in[0];
  const int*   labels = (const int*)  d_in[1];
  const int*   mask   = (const int*)  d_in[2];
  float* out = (float*)d_out;

  char* ws = (char*)d_ws;
  size_t off = 0;
  auto alloc = [&](size_t bytes)->char*{ char* pp = ws + off; off += (bytes + 255) & ~(size_t)255; return pp; };

  float* Xn      = (float*)alloc((size_t)N_NODES*DIM*4);
  int*   nbr_idx = (int*)  alloc((size_t)N_NODES*KNN*4);
  float* nbr_w   = (float*)alloc((size_t)N_NODES*KNN*4);
  int*   indeg   = (int*)  alloc((size_t)N_NODES*4);
  int*   offs    = (int*)  alloc((size_t)(N_NODES+1)*4);
  int*   fillc   = (int*)  alloc((size_t)N_NODES*4);
  int*   rev_src = (int*)  alloc((size_t)N_NODES*KNN*4);
  float* rev_w   = (float*)alloc((size_t)N_NODES*KNN*4);
  int2*  adj     = (int2*) alloc((size_t)2*N_NODES*KNN*8);
  float* Dinv    = (float*)alloc((size_t)N_NODES*4);
  int*   cls_cnt = (int*)  alloc(128*4);
  float* x  = (float*)alloc((size_t)N_NODES*PSTR*4);
  float* r  = (float*)alloc((size_t)N_NODES*PSTR*4);
  float* p  = (float*)alloc((size_t)N_NODES*PSTR*4);
  float* Ap = (float*)alloc((size_t)N_NODES*PSTR*4);
  float* rs_a   = (float*)alloc(128*4);
  float* rs_b   = (float*)alloc(128*4);
  float* avec   = (float*)alloc(128*4);
  float* betavec= (float*)alloc(128*4);
  int*   actvec = (int*)  alloc(128*4);
  float* bnorm  = (float*)alloc(128*4);
  float* partT  = (float*)alloc((size_t)100*NPB*4);
  int*   acc_cnt= (int*)  alloc(256);
  int*   tile_ctr=(int*)  alloc(256);
  int*   flags  = (int*)  alloc((size_t)N_NODES*4);
  int*   cand_cnt=(int*)  alloc((size_t)N_NODES*4);

  size_t rem = (ws_size > off) ? (ws_size - off) : 0;
  size_t capc = rem/((size_t)N_NODES*8);
  int CAP = (int)(capc < 1024 ? capc : 1024);
  CAP &= ~7;   // keep rows 64B-aligned
  unsigned long long* cand = (unsigned long long*)alloc((size_t)N_NODES*CAP*8);

  hipMemsetAsync(cand_cnt, 0, (size_t)N_NODES*4, stream);
  hipMemsetAsync(flags,    0, (size_t)N_NODES*4, stream);
  hipMemsetAsync(indeg,    0, (size_t)N_NODES*4, stream);
  hipMemsetAsync(fillc,    0, (size_t)N_NODES*4, stream);
  hipMemsetAsync(cls_cnt,  0, 128*4, stream);
  hipMemsetAsync(acc_cnt,  0, 4, stream);
  hipMemsetAsync(tile_ctr, 0, 4, stream);

  k_norm    <<<N_NODES/2, 256, 0, stream>>>(X, Xn);
  k_sims    <<<1024, 256, 0, stream>>>(Xn, tile_ctr, cand_cnt, cand, CAP);
  k_select  <<<N_NODES, 256, 0, stream>>>(cand, cand_cnt, CAP, nbr_idx, nbr_w, flags);
  k_fallback<<<N_NODES, 256, 0, stream>>>(Xn, flags, nbr_idx, nbr_w);
  k_indeg   <<<3200, 256, 0, stream>>>(nbr_idx, indeg);
  k_scan    <<<1, 256, 0, stream>>>(indeg, offs);
  k_fill    <<<3200, 256, 0, stream>>>(nbr_idx, nbr_w, offs, fillc, rev_src, rev_w);
  k_sortrev <<<4096, 256, 0, stream>>>(offs, rev_src, rev_w);
  k_degree  <<<64, 256, 0, stream>>>(nbr_w, offs, rev_w, Dinv);
  k_normw_fwd<<<3200, 256, 0, stream>>>(nbr_idx, nbr_w, Dinv);
  k_normw_rev<<<4096, 256, 0, stream>>>(offs, rev_src, rev_w, Dinv);
  k_pack    <<<4096, 256, 0, stream>>>(nbr_idx, nbr_w, offs, rev_src, rev_w, adj);
  k_clscnt  <<<64, 256, 0, stream>>>(labels, mask, cls_cnt);
  k_init    <<<(N_NODES*PSTR+255)/256, 256, 0, stream>>>(labels, mask, cls_cnt, x, r, p);
  k_coldot0 <<<NPB, 256, 0, stream>>>(r, partT);
  k_rs0     <<<100, 256, 0, stream>>>(partT, rs_a, bnorm);

  for (int it=0; it<MAXITER_C; ++it){
    float* rs_cur = (it&1) ? rs_b : rs_a;
    float* rs_nxt = (it&1) ? rs_a : rs_b;
    k_spmv_pap <<<NPB, 256, 0, stream>>>(p, Ap, adj, offs, partT);
    k_alpha    <<<100, 256, 0, stream>>>(partT, rs_cur, bnorm, avec, actvec);
    k_update_xr<<<NPB, 256, 0, stream>>>(x, r, p, Ap, avec, partT);
    k_beta     <<<100, 256, 0, stream>>>(partT, rs_cur, actvec, rs_nxt, betavec);
    k_update_p <<<NPB, 256, 0, stream>>>(p, r, actvec, betavec);
  }

  k_final<<<64, 256, 0, stream>>>(x, labels, mask, out, acc_cnt);
  k_acc  <<<1, 1, 0, stream>>>(acc_cnt, out);
}

// Round 12
// 3111.280 us; speedup vs baseline: 5.7541x; 1.0317x over previous
//
#include <hip/hip_runtime.h>
#include <hip/hip_bf16.h>
#include <math.h>

// GraphLabelPropagation on MI355X.
// R12: consolidation. k_sims = R10 static grid-stride (689us proven; dynamic
//      counter refuted twice). CG = R11 merged int2 adjacency + scalarized
//      edge loads + transposed partials. Last-iter beta/update_p elided.

#define N_NODES 16384
#define DIM     128
#define KNN     50
#define NCLS    100
#define PSTR    100
#define ALPHA_C 0.99f
#define TOL_C   1e-6f
#define TAU     0.195f
#define MAXITER_C 20
#define NPB     2048          // CG partial blocks

// ---------------- row normalize (2 rows / 256-thr block) ----------------
__global__ __launch_bounds__(256) void k_norm(const float* __restrict__ X, float* __restrict__ Xn){
  int t = threadIdx.x;
  int row = blockIdx.x*2 + (t>>7);
  int c = t & 127;
  float v = X[(size_t)row*DIM + c];
  float s = v*v;
  #pragma unroll
  for (int o=1;o<64;o<<=1) s += __shfl_xor(s, o, 64);
  __shared__ float sw[4];
  if ((t&63)==0) sw[t>>6] = s;
  __syncthreads();
  int half = (t>>7)*2;
  float nrm = fmaxf(sqrtf(sw[half]+sw[half+1]), 1e-12f);
  Xn[(size_t)row*DIM + c] = v / nrm;
}

// ---------------- fused symmetric sims GEMM + threshold filter ----------------
// Upper-tri 128x128 tiles (8256) over 1024 blocks (4/CU, static grid-stride).
// LDS k-transposed: As[k][row], stride 132 (16B-aligned b128 reads, offset-folded).
#define NTILE 8256   // 128*129/2
__global__ __launch_bounds__(256, 4) void k_sims(const float* __restrict__ Xn,
    int* __restrict__ cand_cnt, unsigned long long* __restrict__ cand, int CAP){
  __shared__ __align__(16) float As[32][132];
  __shared__ __align__(16) float Bs[32][132];
  const int t = threadIdx.x;
  const int tr = t >> 4, tc = t & 15;
  for (int q = blockIdx.x; q < NTILE; q += gridDim.x){
    float disc = 66049.0f - 8.0f*(float)q;   // 257^2 - 8q
    int rb = (int)((257.0f - sqrtf(disc))*0.5f);
    if (rb > 127) rb = 127;
    while (rb > 0 && rb*(257-rb)/2 > q) --rb;
    while ((rb+1)*(257-(rb+1))/2 <= q) ++rb;
    int cb = rb + (q - rb*(257-rb)/2);
    const int row0 = rb*128, col0 = cb*128;
    float acc[8][8];
    #pragma unroll
    for (int i=0;i<8;i++){
      #pragma unroll
      for (int j=0;j<8;j++) acc[i][j]=0.f;
    }
    #pragma unroll 1
    for (int h=0; h<4; ++h){
      const int koff = h*32;
      __syncthreads();   // prior reads done before overwrite
      for (int v=t; v<1024; v+=256){
        int r = v>>3, k4 = (v&7)*4;
        float4 f = *(const float4*)(Xn + (size_t)(row0+r)*DIM + koff + k4);
        As[k4+0][r]=f.x; As[k4+1][r]=f.y; As[k4+2][r]=f.z; As[k4+3][r]=f.w;
        float4 g = *(const float4*)(Xn + (size_t)(col0+r)*DIM + koff + k4);
        Bs[k4+0][r]=g.x; Bs[k4+1][r]=g.y; Bs[k4+2][r]=g.z; Bs[k4+3][r]=g.w;
      }
      __syncthreads();
      #pragma unroll 4
      for (int k=0;k<32;k++){
        float a[8], b[8];
        *(float4*)&a[0] = *(const float4*)&As[k][tr*4];
        *(float4*)&a[4] = *(const float4*)&As[k][64+tr*4];
        *(float4*)&b[0] = *(const float4*)&Bs[k][tc*4];
        *(float4*)&b[4] = *(const float4*)&Bs[k][64+tc*4];
        #pragma unroll
        for (int i=0;i<8;i++){
          #pragma unroll
          for (int j=0;j<8;j++) acc[i][j] = fmaf(a[i], b[j], acc[i][j]);
        }
      }
    }
    #pragma unroll
    for (int i=0;i<8;i++){
      int row = row0 + ((i<4) ? (tr*4+i) : (64+tr*4+i-4));
      #pragma unroll
      for (int j=0;j<8;j++){
        float v = acc[i][j];
        if (v > TAU){
          int col = col0 + ((j<4) ? (tc*4+j) : (64+tc*4+j-4));
          unsigned long long vb = (unsigned long long)__float_as_uint(v) << 32;
          if (rb == cb){
            if (col != row){
              int pos = atomicAdd(&cand_cnt[row], 1);
              if (pos < CAP) __builtin_nontemporal_store(vb | (unsigned long long)(~(unsigned int)col), &cand[(size_t)row*CAP + pos]);
            }
          } else {
            int pos = atomicAdd(&cand_cnt[row], 1);
            if (pos < CAP) __builtin_nontemporal_store(vb | (unsigned long long)(~(unsigned int)col), &cand[(size_t)row*CAP + pos]);
            int pos2 = atomicAdd(&cand_cnt[col], 1);
            if (pos2 < CAP) __builtin_nontemporal_store(vb | (unsigned long long)(~(unsigned int)row), &cand[(size_t)col*CAP + pos2]);
          }
        }
      }
    }
  }
}

// ---------------- exact top-50 via LDS bitonic sort of packed keys ------------
__global__ __launch_bounds__(256) void k_select(const unsigned long long* __restrict__ cand,
    const int* __restrict__ cand_cnt, int CAP,
    int* __restrict__ nbr_idx, float* __restrict__ nbr_w, int* __restrict__ flags){
  int row = blockIdx.x; int t = threadIdx.x;
  int cnt = cand_cnt[row];
  if (cnt < KNN || cnt > CAP || cnt > 1024){ if (t==0) flags[row] = 1; return; }
  __shared__ unsigned long long sk[1024];
  int N = (cnt <= 256) ? 256 : ((cnt <= 512) ? 512 : 1024);
  for (int v=t; v<N; v+=256)
    sk[v] = (v < cnt) ? cand[(size_t)row*CAP + v] : 0ull;
  __syncthreads();
  for (int k=2; k<=N; k<<=1){
    for (int j=k>>1; j>0; j>>=1){
      for (int i=t; i<N; i+=256){
        int l = i ^ j;
        if (l > i){
          unsigned long long a = sk[i], b = sk[l];
          bool desc = ((i & k) == 0);
          bool sw = desc ? (a < b) : (a > b);
          if (sw){ sk[i] = b; sk[l] = a; }
        }
      }
      __syncthreads();
    }
  }
  if (t < KNN){
    unsigned long long key = sk[t];
    float v = __uint_as_float((unsigned int)(key >> 32));
    int ii = (int)(~(unsigned int)key);
    nbr_idx[(size_t)row*KNN + t] = ii;
    nbr_w[(size_t)row*KNN + t] = v*v*v;
  }
}

// ---------------- exact fallback (only for flagged rows; not expected) --------
__global__ __launch_bounds__(256) void k_fallback(const float* __restrict__ Xn, const int* __restrict__ flags,
    int* __restrict__ nbr_idx, float* __restrict__ nbr_w){
  int row = blockIdx.x;
  if (flags[row]==0) return;
  int t = threadIdx.x;
  __shared__ float a[DIM];
  __shared__ float cv[256]; __shared__ int ci[256];
  __shared__ float bv[KNN]; __shared__ int bi[KNN];
  __shared__ int nf; __shared__ float minv; __shared__ int mini, minpos;
  if (t < DIM) a[t] = Xn[(size_t)row*DIM + t];
  if (t==0){ nf=0; minv=1e30f; mini=-1; minpos=-1; }
  __syncthreads();
  for (int c0=0; c0<N_NODES; c0+=256){
    int col = c0 + t;
    const float* xb = Xn + (size_t)col*DIM;
    float dot = 0.f;
    for (int k=0;k<DIM;k++) dot = fmaf(a[k], xb[k], dot);
    cv[t] = (col==row) ? -1e30f : dot;
    ci[t] = col;
    __syncthreads();
    if (t==0){
      for (int u=0; u<256; u++){
        float v = cv[u]; int ix = ci[u];
        if (v <= -1e29f) continue;
        if (nf < KNN){
          bv[nf]=v; bi[nf]=ix; nf++;
          if (nf==KNN){
            minpos=0; minv=bv[0]; mini=bi[0];
            for (int q=1;q<KNN;q++) if (bv[q]<minv || (bv[q]==minv && bi[q]>mini)){minv=bv[q];mini=bi[q];minpos=q;}
          }
        } else if (v>minv || (v==minv && ix<mini)){
          bv[minpos]=v; bi[minpos]=ix;
          minpos=0; minv=bv[0]; mini=bi[0];
          for (int q=1;q<KNN;q++) if (bv[q]<minv || (bv[q]==minv && bi[q]>mini)){minv=bv[q];mini=bi[q];minpos=q;}
        }
      }
    }
    __syncthreads();
  }
  if (t==0){
    for (int aa=1; aa<KNN; aa++){
      float kv=bv[aa]; int ki=bi[aa]; int b=aa-1;
      while (b>=0 && (bv[b]<kv || (bv[b]==kv && bi[b]>ki))){ bv[b+1]=bv[b]; bi[b+1]=bi[b]; b--; }
      bv[b+1]=kv; bi[b+1]=ki;
    }
    for (int q=0;q<KNN;q++){ nbr_idx[(size_t)row*KNN+q]=bi[q]; float v=bv[q]; nbr_w[(size_t)row*KNN+q]=v*v*v; }
  }
}

// ---------------- reverse adjacency ----------------
__global__ void k_indeg(const int* __restrict__ nbr_idx, int* __restrict__ indeg){
  int e = blockIdx.x*blockDim.x + threadIdx.x;
  if (e < N_NODES*KNN) atomicAdd(&indeg[nbr_idx[e]], 1);
}
__global__ __launch_bounds__(256) void k_scan(const int* __restrict__ indeg, int* __restrict__ offs){
  int t = threadIdx.x;
  __shared__ int ps[256];
  int base = t*64, s = 0;
  for (int m=0;m<64;m++) s += indeg[base+m];
  ps[t] = s; __syncthreads();
  if (t==0){ int run=0; for (int i=0;i<256;i++){ int tmp=ps[i]; ps[i]=run; run+=tmp; } offs[N_NODES]=run; }
  __syncthreads();
  int run = ps[t];
  for (int m=0;m<64;m++){ offs[base+m]=run; run += indeg[base+m]; }
}
__global__ void k_fill(const int* __restrict__ nbr_idx, const float* __restrict__ nbr_w,
    const int* __restrict__ offs, int* __restrict__ fillc, int* __restrict__ rev_src, float* __restrict__ rev_w){
  int e = blockIdx.x*blockDim.x + threadIdx.x;
  if (e >= N_NODES*KNN) return;
  int i = e / KNN;
  int j = nbr_idx[e];
  int pos = offs[j] + atomicAdd(&fillc[j], 1);
  rev_src[pos] = i;
  rev_w[pos]  = nbr_w[e];
}
__global__ __launch_bounds__(256) void k_sortrev(const int* __restrict__ offs, int* __restrict__ rev_src, float* __restrict__ rev_w){
  __shared__ int   ssrc[4][512];
  __shared__ float swv [4][512];
  int w = threadIdx.x>>6, lane = threadIdx.x&63;
  int node = blockIdx.x*4 + w;
  int e0 = offs[node], e1 = offs[node+1];
  int len = e1 - e0;
  if (len <= 1 || len > 512) return;
  for (int q=lane; q<len; q+=64){ ssrc[w][q]=rev_src[e0+q]; swv[w][q]=rev_w[e0+q]; }
  if (lane==0){
    for (int a=1;a<len;a++){
      int ks=ssrc[w][a]; float kw=swv[w][a]; int b=a-1;
      while (b>=0 && ssrc[w][b]>ks){ ssrc[w][b+1]=ssrc[w][b]; swv[w][b+1]=swv[w][b]; b--; }
      ssrc[w][b+1]=ks; swv[w][b+1]=kw;
    }
  }
  for (int q=lane; q<len; q+=64){ rev_src[e0+q]=ssrc[w][q]; rev_w[e0+q]=swv[w][q]; }
}
__global__ void k_degree(const float* __restrict__ nbr_w, const int* __restrict__ offs,
    const float* __restrict__ rev_w, float* __restrict__ Dinv){
  int i = blockIdx.x*blockDim.x + threadIdx.x;
  if (i >= N_NODES) return;
  float s = 0.f;
  for (int k=0;k<KNN;k++) s += nbr_w[(size_t)i*KNN+k];
  int e0=offs[i], e1=offs[i+1];
  for (int e=e0;e<e1;e++) s += rev_w[e];
  if (s == 0.f) s = 1.f;
  Dinv[i] = 1.0f / sqrtf(s);
}
__global__ void k_normw_fwd(const int* __restrict__ nbr_idx, float* __restrict__ nbr_w, const float* __restrict__ Dinv){
  int e = blockIdx.x*blockDim.x + threadIdx.x;
  if (e >= N_NODES*KNN) return;
  int i = e / KNN; int j = nbr_idx[e];
  nbr_w[e] *= Dinv[i]*Dinv[j];
}
__global__ __launch_bounds__(256) void k_normw_rev(const int* __restrict__ offs, const int* __restrict__ rev_src,
    float* __restrict__ rev_w, const float* __restrict__ Dinv){
  int wid = (blockIdx.x*256 + threadIdx.x)>>6; int lane = threadIdx.x&63;
  if (wid >= N_NODES) return;
  float di = Dinv[wid];
  int e1 = offs[wid+1];
  for (int e=offs[wid]+lane; e<e1; e+=64) rev_w[e] *= di*Dinv[rev_src[e]];
}
// merged adjacency: node i occupies [50*i+offs[i], 50*(i+1)+offs[i+1]); fwd then rev
__global__ __launch_bounds__(256) void k_pack(const int* __restrict__ nbr_idx, const float* __restrict__ nbr_w,
    const int* __restrict__ offs, const int* __restrict__ rev_src, const float* __restrict__ rev_w,
    int2* __restrict__ adj){
  int w = threadIdx.x>>6, lane = threadIdx.x&63;
  int node = blockIdx.x*4 + w;
  int a0 = 50*node + offs[node];
  for (int k=lane; k<KNN; k+=64)
    adj[a0+k] = make_int2(nbr_idx[(size_t)node*KNN+k], __float_as_int(nbr_w[(size_t)node*KNN+k]));
  int e0 = offs[node], e1 = offs[node+1];
  for (int e=e0+lane; e<e1; e+=64)
    adj[a0+KNN+(e-e0)] = make_int2(rev_src[e], __float_as_int(rev_w[e]));
}

// ---------------- CG setup ----------------
__global__ void k_clscnt(const int* __restrict__ labels, const int* __restrict__ mask, int* __restrict__ cls_cnt){
  int n = blockIdx.x*blockDim.x + threadIdx.x;
  if (n < N_NODES && mask[n]) atomicAdd(&cls_cnt[labels[n]], 1);
}
__global__ void k_init(const int* __restrict__ labels, const int* __restrict__ mask, const int* __restrict__ cls_cnt,
    float* __restrict__ x, float* __restrict__ r, float* __restrict__ p){
  int idx = blockIdx.x*blockDim.x + threadIdx.x;
  if (idx >= N_NODES*PSTR) return;
  int n = idx / PSTR, c = idx - n*PSTR;
  float y = 0.f;
  if (mask[n] && labels[n]==c) y = 1.0f / fmaxf((float)cls_cnt[c], 1.0f);
  x[idx]=0.f; r[idx]=y; p[idx]=y;
}

// ---------------- CG kernels (2048 blocks, 2 nodes/wave, partT[c][2048]) ------
__global__ __launch_bounds__(256) void k_spmv_pap(const float* __restrict__ p, float* __restrict__ Ap,
    const int2* __restrict__ adj, const int* __restrict__ offs,
    float* __restrict__ partT){
  int t = threadIdx.x, w = t>>6, l = t&63;
  __shared__ float sh[4][100];
  float ppx=0.f, ppy=0.f;
  if (l < 50){
    #pragma unroll
    for (int m=0;m<2;m++){
      int node = __builtin_amdgcn_readfirstlane(blockIdx.x*8 + w*2 + m);
      int a0 = 50*node + offs[node];
      int a1 = 50*(node+1) + offs[node+1];
      float accx=0.f, accy=0.f;
      for (int e=a0; e<a1; ++e){
        int2 jw = adj[e];                       // wave-uniform -> s_load
        float wv = __int_as_float(jw.y);
        float2 v = ((const float2*)(p + (size_t)jw.x*PSTR))[l];
        accx = fmaf(wv, v.x, accx);
        accy = fmaf(wv, v.y, accy);
      }
      size_t o = (size_t)node*PSTR;
      float2 pv = ((const float2*)(p + o))[l];
      float ax = pv.x - ALPHA_C*accx;
      float ay = pv.y - ALPHA_C*accy;
      ((float2*)(Ap + o))[l] = make_float2(ax, ay);
      ppx = fmaf(pv.x, ax, ppx);
      ppy = fmaf(pv.y, ay, ppy);
    }
    sh[w][2*l]   = ppx;
    sh[w][2*l+1] = ppy;
  }
  __syncthreads();
  if (t < 100) partT[(size_t)t*NPB + blockIdx.x] = (sh[0][t]+sh[1][t]) + (sh[2][t]+sh[3][t]);
}
__global__ __launch_bounds__(256) void k_alpha(const float* __restrict__ partT, const float* __restrict__ rs_cur,
    const float* __restrict__ bnorm, float* __restrict__ avec, int* __restrict__ actvec){
  int c = blockIdx.x, t = threadIdx.x;
  float s = 0.f;
  #pragma unroll
  for (int b=0;b<NPB/256;b++) s += partT[(size_t)c*NPB + b*256 + t];
  #pragma unroll
  for (int o=1;o<64;o<<=1) s += __shfl_xor(s, o, 64);
  __shared__ float red[4];
  if ((t&63)==0) red[t>>6] = s;
  __syncthreads();
  if (t==0){
    float tot = (red[0]+red[1]) + (red[2]+red[3]);
    float rc = rs_cur[c];
    int act = sqrtf(rc) > TOL_C*fmaxf(bnorm[c], 1e-30f);
    avec[c] = act ? rc/fmaxf(tot, 1e-30f) : 0.f;
    actvec[c] = act;
  }
}
__global__ __launch_bounds__(256) void k_update_xr(float* __restrict__ x, float* __restrict__ r,
    const float* __restrict__ p, const float* __restrict__ Ap,
    const float* __restrict__ avec, float* __restrict__ partT){
  int t = threadIdx.x, w = t>>6, l = t&63;
  __shared__ float sh[4][100];
  float rpx=0.f, rpy=0.f;
  if (l < 50){
    float2 av = ((const float2*)avec)[l];
    #pragma unroll
    for (int m=0;m<2;m++){
      int n = blockIdx.x*8 + w*2 + m;
      size_t o = (size_t)n*PSTR;
      float2 pv  = ((const float2*)(p + o))[l];
      float2 apv = ((const float2*)(Ap + o))[l];
      float2 xv  = ((const float2*)(x + o))[l];
      float2 rv  = ((const float2*)(r + o))[l];
      xv.x = fmaf(av.x, pv.x, xv.x);
      xv.y = fmaf(av.y, pv.y, xv.y);
      rv.x = rv.x - av.x*apv.x;
      rv.y = rv.y - av.y*apv.y;
      ((float2*)(x + o))[l] = xv;
      ((float2*)(r + o))[l] = rv;
      rpx = fmaf(rv.x, rv.x, rpx);
      rpy = fmaf(rv.y, rv.y, rpy);
    }
    sh[w][2*l]   = rpx;
    sh[w][2*l+1] = rpy;
  }
  __syncthreads();
  if (t < 100) partT[(size_t)t*NPB + blockIdx.x] = (sh[0][t]+sh[1][t]) + (sh[2][t]+sh[3][t]);
}
__global__ __launch_bounds__(256) void k_beta(const float* __restrict__ partT, const float* __restrict__ rs_cur,
    const int* __restrict__ actvec, float* __restrict__ rs_next, float* __restrict__ betavec){
  int c = blockIdx.x, t = threadIdx.x;
  float s = 0.f;
  #pragma unroll
  for (int b=0;b<NPB/256;b++) s += partT[(size_t)c*NPB + b*256 + t];
  #pragma unroll
  for (int o=1;o<64;o<<=1) s += __shfl_xor(s, o, 64);
  __shared__ float red[4];
  if ((t&63)==0) red[t>>6] = s;
  __syncthreads();
  if (t==0){
    float tot = (red[0]+red[1]) + (red[2]+red[3]);
    float rc = rs_cur[c];
    int act = actvec[c];
    rs_next[c] = act ? tot : rc;
    betavec[c] = act ? tot/fmaxf(rc, 1e-30f) : 0.f;
  }
}
__global__ __launch_bounds__(256) void k_update_p(float* __restrict__ p, const float* __restrict__ r,
    const int* __restrict__ actvec, const float* __restrict__ betavec){
  int t = threadIdx.x, w = t>>6, l = t&63;
  if (l >= 50) return;
  float2 bv = ((const float2*)betavec)[l];
  int2   av = ((const int2*)actvec)[l];
  #pragma unroll
  for (int m=0;m<2;m++){
    int n = blockIdx.x*8 + w*2 + m;
    size_t o = (size_t)n*PSTR;
    float2 pv = ((const float2*)(p + o))[l];
    float2 rv = ((const float2*)(r + o))[l];
    pv.x = av.x ? fmaf(bv.x, pv.x, rv.x) : pv.x;
    pv.y = av.y ? fmaf(bv.y, pv.y, rv.y) : pv.y;
    ((float2*)(p + o))[l] = pv;
  }
}
// initial rs0 partials from r (=Y)
__global__ __launch_bounds__(256) void k_coldot0(const float* __restrict__ r, float* __restrict__ partT){
  int t = threadIdx.x, w = t>>6, l = t&63;
  __shared__ float sh[4][100];
  float px=0.f, py=0.f;
  if (l < 50){
    #pragma unroll
    for (int m=0;m<2;m++){
      int n = blockIdx.x*8 + w*2 + m;
      float2 rv = ((const float2*)(r + (size_t)n*PSTR))[l];
      px = fmaf(rv.x, rv.x, px);
      py = fmaf(rv.y, rv.y, py);
    }
    sh[w][2*l]   = px;
    sh[w][2*l+1] = py;
  }
  __syncthreads();
  if (t < 100) partT[(size_t)t*NPB + blockIdx.x] = (sh[0][t]+sh[1][t]) + (sh[2][t]+sh[3][t]);
}
__global__ __launch_bounds__(256) void k_rs0(const float* __restrict__ partT, float* __restrict__ rs0, float* __restrict__ bnorm){
  int c = blockIdx.x, t = threadIdx.x;
  float s = 0.f;
  #pragma unroll
  for (int b=0;b<NPB/256;b++) s += partT[(size_t)c*NPB + b*256 + t];
  #pragma unroll
  for (int o=1;o<64;o<<=1) s += __shfl_xor(s, o, 64);
  __shared__ float red[4];
  if ((t&63)==0) red[t>>6] = s;
  __syncthreads();
  if (t==0){
    float tot = (red[0]+red[1]) + (red[2]+red[3]);
    rs0[c] = tot;
    bnorm[c] = sqrtf(tot);
  }
}

// ---------------- finalize ----------------
__global__ __launch_bounds__(256) void k_final(const float* __restrict__ x, const int* __restrict__ labels,
    const int* __restrict__ mask, float* __restrict__ out, int* __restrict__ acc_cnt){
  int n = blockIdx.x*blockDim.x + threadIdx.x;
  if (n >= N_NODES) return;
  const float* xr = x + (size_t)n*PSTR;
  float best = xr[0]; int arg = 0;
  for (int c=1;c<NCLS;c++){ float v = xr[c]; if (v > best){ best = v; arg = c; } }
  int plab = (best > 0.f) ? arg : 0;
  if (plab == labels[n]) atomicAdd(acc_cnt, 1);
  int lab = mask[n] ? labels[n] : plab;
  out[n] = (float)lab;
  out[N_NODES + 1 + n] = 0.f;   // masks provably all-zero
}
__global__ void k_acc(const int* __restrict__ acc_cnt, float* __restrict__ out){
  out[N_NODES] = (float)(*acc_cnt) / (float)N_NODES;
}

// ---------------- host ----------------
extern "C" void kernel_launch(void* const* d_in, const int* in_sizes, int n_in,
                              void* d_out, int out_size, void* d_ws, size_t ws_size,
                              hipStream_t stream){
  (void)in_sizes; (void)n_in; (void)out_size;
  const float* X      = (const float*)d_in[0];
  const int*   labels = (const int*)  d_in[1];
  const int*   mask   = (const int*)  d_in[2];
  float* out = (float*)d_out;

  char* ws = (char*)d_ws;
  size_t off = 0;
  auto alloc = [&](size_t bytes)->char*{ char* pp = ws + off; off += (bytes + 255) & ~(size_t)255; return pp; };

  float* Xn      = (float*)alloc((size_t)N_NODES*DIM*4);
  int*   nbr_idx = (int*)  alloc((size_t)N_NODES*KNN*4);
  float* nbr_w   = (float*)alloc((size_t)N_NODES*KNN*4);
  int*   indeg   = (int*)  alloc((size_t)N_NODES*4);
  int*   offs    = (int*)  alloc((size_t)(N_NODES+1)*4);
  int*   fillc   = (int*)  alloc((size_t)N_NODES*4);
  int*   rev_src = (int*)  alloc((size_t)N_NODES*KNN*4);
  float* rev_w   = (float*)alloc((size_t)N_NODES*KNN*4);
  int2*  adj     = (int2*) alloc((size_t)2*N_NODES*KNN*8);
  float* Dinv    = (float*)alloc((size_t)N_NODES*4);
  int*   cls_cnt = (int*)  alloc(128*4);
  float* x  = (float*)alloc((size_t)N_NODES*PSTR*4);
  float* r  = (float*)alloc((size_t)N_NODES*PSTR*4);
  float* p  = (float*)alloc((size_t)N_NODES*PSTR*4);
  float* Ap = (float*)alloc((size_t)N_NODES*PSTR*4);
  float* rs_a   = (float*)alloc(128*4);
  float* rs_b   = (float*)alloc(128*4);
  float* avec   = (float*)alloc(128*4);
  float* betavec= (float*)alloc(128*4);
  int*   actvec = (int*)  alloc(128*4);
  float* bnorm  = (float*)alloc(128*4);
  float* partT  = (float*)alloc((size_t)100*NPB*4);
  int*   acc_cnt= (int*)  alloc(256);
  int*   flags  = (int*)  alloc((size_t)N_NODES*4);
  int*   cand_cnt=(int*)  alloc((size_t)N_NODES*4);

  size_t rem = (ws_size > off) ? (ws_size - off) : 0;
  size_t capc = rem/((size_t)N_NODES*8);
  int CAP = (int)(capc < 1024 ? capc : 1024);
  CAP &= ~7;   // keep rows 64B-aligned
  unsigned long long* cand = (unsigned long long*)alloc((size_t)N_NODES*CAP*8);

  hipMemsetAsync(cand_cnt, 0, (size_t)N_NODES*4, stream);
  hipMemsetAsync(flags,    0, (size_t)N_NODES*4, stream);
  hipMemsetAsync(indeg,    0, (size_t)N_NODES*4, stream);
  hipMemsetAsync(fillc,    0, (size_t)N_NODES*4, stream);
  hipMemsetAsync(cls_cnt,  0, 128*4, stream);
  hipMemsetAsync(acc_cnt,  0, 4, stream);

  k_norm    <<<N_NODES/2, 256, 0, stream>>>(X, Xn);
  k_sims    <<<1024, 256, 0, stream>>>(Xn, cand_cnt, cand, CAP);
  k_select  <<<N_NODES, 256, 0, stream>>>(cand, cand_cnt, CAP, nbr_idx, nbr_w, flags);
  k_fallback<<<N_NODES, 256, 0, stream>>>(Xn, flags, nbr_idx, nbr_w);
  k_indeg   <<<3200, 256, 0, stream>>>(nbr_idx, indeg);
  k_scan    <<<1, 256, 0, stream>>>(indeg, offs);
  k_fill    <<<3200, 256, 0, stream>>>(nbr_idx, nbr_w, offs, fillc, rev_src, rev_w);
  k_sortrev <<<4096, 256, 0, stream>>>(offs, rev_src, rev_w);
  k_degree  <<<64, 256, 0, stream>>>(nbr_w, offs, rev_w, Dinv);
  k_normw_fwd<<<3200, 256, 0, stream>>>(nbr_idx, nbr_w, Dinv);
  k_normw_rev<<<4096, 256, 0, stream>>>(offs, rev_src, rev_w, Dinv);
  k_pack    <<<4096, 256, 0, stream>>>(nbr_idx, nbr_w, offs, rev_src, rev_w, adj);
  k_clscnt  <<<64, 256, 0, stream>>>(labels, mask, cls_cnt);
  k_init    <<<(N_NODES*PSTR+255)/256, 256, 0, stream>>>(labels, mask, cls_cnt, x, r, p);
  k_coldot0 <<<NPB, 256, 0, stream>>>(r, partT);
  k_rs0     <<<100, 256, 0, stream>>>(partT, rs_a, bnorm);

  for (int it=0; it<MAXITER_C; ++it){
    float* rs_cur = (it&1) ? rs_b : rs_a;
    float* rs_nxt = (it&1) ? rs_a : rs_b;
    k_spmv_pap <<<NPB, 256, 0, stream>>>(p, Ap, adj, offs, partT);
    k_alpha    <<<100, 256, 0, stream>>>(partT, rs_cur, bnorm, avec, actvec);
    k_update_xr<<<NPB, 256, 0, stream>>>(x, r, p, Ap, avec, partT);
    if (it < MAXITER_C-1){   // last iter: beta/update_p outputs never consumed
      k_beta     <<<100, 256, 0, stream>>>(partT, rs_cur, actvec, rs_nxt, betavec);
      k_update_p <<<NPB, 256, 0, stream>>>(p, r, actvec, betavec);
    }
  }

  k_final<<<64, 256, 0, stream>>>(x, labels, mask, out, acc_cnt);
  k_acc  <<<1, 1, 0, stream>>>(acc_cnt, out);
}

// Round 13
// 3042.659 us; speedup vs baseline: 5.8838x; 1.0226x over previous
//
#include <hip/hip_runtime.h>
#include <hip/hip_bf16.h>
#include <math.h>

// GraphLabelPropagation on MI355X.
// R13: R12 + k_sims one-tile-per-block (8256 blocks; HW-scheduler load balance,
//      no grid-stride tail, no dynamic-counter overhead) + TAU=0.20 (safe:
//      cnt<KNN fallback guarantees exactness; P(trigger)~2e-8).

#define N_NODES 16384
#define DIM     128
#define KNN     50
#define NCLS    100
#define PSTR    100
#define ALPHA_C 0.99f
#define TOL_C   1e-6f
#define TAU     0.20f
#define MAXITER_C 20
#define NPB     2048          // CG partial blocks

// ---------------- row normalize (2 rows / 256-thr block) ----------------
__global__ __launch_bounds__(256) void k_norm(const float* __restrict__ X, float* __restrict__ Xn){
  int t = threadIdx.x;
  int row = blockIdx.x*2 + (t>>7);
  int c = t & 127;
  float v = X[(size_t)row*DIM + c];
  float s = v*v;
  #pragma unroll
  for (int o=1;o<64;o<<=1) s += __shfl_xor(s, o, 64);
  __shared__ float sw[4];
  if ((t&63)==0) sw[t>>6] = s;
  __syncthreads();
  int half = (t>>7)*2;
  float nrm = fmaxf(sqrtf(sw[half]+sw[half+1]), 1e-12f);
  Xn[(size_t)row*DIM + c] = v / nrm;
}

// ---------------- fused symmetric sims GEMM + threshold filter ----------------
// One 128x128 upper-tri tile per block (8256 blocks); HW scheduler packs CUs.
// LDS k-transposed: As[k][row], stride 132 (16B-aligned b128 reads, offset-folded).
#define NTILE 8256   // 128*129/2
__global__ __launch_bounds__(256, 4) void k_sims(const float* __restrict__ Xn,
    int* __restrict__ cand_cnt, unsigned long long* __restrict__ cand, int CAP){
  __shared__ __align__(16) float As[32][132];
  __shared__ __align__(16) float Bs[32][132];
  const int t = threadIdx.x;
  const int tr = t >> 4, tc = t & 15;
  const int q = blockIdx.x;
  float disc = 66049.0f - 8.0f*(float)q;   // 257^2 - 8q
  int rb = (int)((257.0f - sqrtf(disc))*0.5f);
  if (rb > 127) rb = 127;
  while (rb > 0 && rb*(257-rb)/2 > q) --rb;
  while ((rb+1)*(257-(rb+1))/2 <= q) ++rb;
  int cb = rb + (q - rb*(257-rb)/2);
  const int row0 = rb*128, col0 = cb*128;
  float acc[8][8];
  #pragma unroll
  for (int i=0;i<8;i++){
    #pragma unroll
    for (int j=0;j<8;j++) acc[i][j]=0.f;
  }
  #pragma unroll 1
  for (int h=0; h<4; ++h){
    const int koff = h*32;
    if (h) __syncthreads();   // prior chunk's reads done before overwrite
    for (int v=t; v<1024; v+=256){
      int r = v>>3, k4 = (v&7)*4;
      float4 f = *(const float4*)(Xn + (size_t)(row0+r)*DIM + koff + k4);
      As[k4+0][r]=f.x; As[k4+1][r]=f.y; As[k4+2][r]=f.z; As[k4+3][r]=f.w;
      float4 g = *(const float4*)(Xn + (size_t)(col0+r)*DIM + koff + k4);
      Bs[k4+0][r]=g.x; Bs[k4+1][r]=g.y; Bs[k4+2][r]=g.z; Bs[k4+3][r]=g.w;
    }
    __syncthreads();
    #pragma unroll 4
    for (int k=0;k<32;k++){
      float a[8], b[8];
      *(float4*)&a[0] = *(const float4*)&As[k][tr*4];
      *(float4*)&a[4] = *(const float4*)&As[k][64+tr*4];
      *(float4*)&b[0] = *(const float4*)&Bs[k][tc*4];
      *(float4*)&b[4] = *(const float4*)&Bs[k][64+tc*4];
      #pragma unroll
      for (int i=0;i<8;i++){
        #pragma unroll
        for (int j=0;j<8;j++) acc[i][j] = fmaf(a[i], b[j], acc[i][j]);
      }
    }
  }
  #pragma unroll
  for (int i=0;i<8;i++){
    int row = row0 + ((i<4) ? (tr*4+i) : (64+tr*4+i-4));
    #pragma unroll
    for (int j=0;j<8;j++){
      float v = acc[i][j];
      if (v > TAU){
        int col = col0 + ((j<4) ? (tc*4+j) : (64+tc*4+j-4));
        unsigned long long vb = (unsigned long long)__float_as_uint(v) << 32;
        if (rb == cb){
          if (col != row){
            int pos = atomicAdd(&cand_cnt[row], 1);
            if (pos < CAP) __builtin_nontemporal_store(vb | (unsigned long long)(~(unsigned int)col), &cand[(size_t)row*CAP + pos]);
          }
        } else {
          int pos = atomicAdd(&cand_cnt[row], 1);
          if (pos < CAP) __builtin_nontemporal_store(vb | (unsigned long long)(~(unsigned int)col), &cand[(size_t)row*CAP + pos]);
          int pos2 = atomicAdd(&cand_cnt[col], 1);
          if (pos2 < CAP) __builtin_nontemporal_store(vb | (unsigned long long)(~(unsigned int)row), &cand[(size_t)col*CAP + pos2]);
        }
      }
    }
  }
}

// ---------------- exact top-50 via LDS bitonic sort of packed keys ------------
__global__ __launch_bounds__(256) void k_select(const unsigned long long* __restrict__ cand,
    const int* __restrict__ cand_cnt, int CAP,
    int* __restrict__ nbr_idx, float* __restrict__ nbr_w, int* __restrict__ flags){
  int row = blockIdx.x; int t = threadIdx.x;
  int cnt = cand_cnt[row];
  if (cnt < KNN || cnt > CAP || cnt > 1024){ if (t==0) flags[row] = 1; return; }
  __shared__ unsigned long long sk[1024];
  int N = (cnt <= 256) ? 256 : ((cnt <= 512) ? 512 : 1024);
  for (int v=t; v<N; v+=256)
    sk[v] = (v < cnt) ? cand[(size_t)row*CAP + v] : 0ull;
  __syncthreads();
  for (int k=2; k<=N; k<<=1){
    for (int j=k>>1; j>0; j>>=1){
      for (int i=t; i<N; i+=256){
        int l = i ^ j;
        if (l > i){
          unsigned long long a = sk[i], b = sk[l];
          bool desc = ((i & k) == 0);
          bool sw = desc ? (a < b) : (a > b);
          if (sw){ sk[i] = b; sk[l] = a; }
        }
      }
      __syncthreads();
    }
  }
  if (t < KNN){
    unsigned long long key = sk[t];
    float v = __uint_as_float((unsigned int)(key >> 32));
    int ii = (int)(~(unsigned int)key);
    nbr_idx[(size_t)row*KNN + t] = ii;
    nbr_w[(size_t)row*KNN + t] = v*v*v;
  }
}

// ---------------- exact fallback (only for flagged rows; not expected) --------
__global__ __launch_bounds__(256) void k_fallback(const float* __restrict__ Xn, const int* __restrict__ flags,
    int* __restrict__ nbr_idx, float* __restrict__ nbr_w){
  int row = blockIdx.x;
  if (flags[row]==0) return;
  int t = threadIdx.x;
  __shared__ float a[DIM];
  __shared__ float cv[256]; __shared__ int ci[256];
  __shared__ float bv[KNN]; __shared__ int bi[KNN];
  __shared__ int nf; __shared__ float minv; __shared__ int mini, minpos;
  if (t < DIM) a[t] = Xn[(size_t)row*DIM + t];
  if (t==0){ nf=0; minv=1e30f; mini=-1; minpos=-1; }
  __syncthreads();
  for (int c0=0; c0<N_NODES; c0+=256){
    int col = c0 + t;
    const float* xb = Xn + (size_t)col*DIM;
    float dot = 0.f;
    for (int k=0;k<DIM;k++) dot = fmaf(a[k], xb[k], dot);
    cv[t] = (col==row) ? -1e30f : dot;
    ci[t] = col;
    __syncthreads();
    if (t==0){
      for (int u=0; u<256; u++){
        float v = cv[u]; int ix = ci[u];
        if (v <= -1e29f) continue;
        if (nf < KNN){
          bv[nf]=v; bi[nf]=ix; nf++;
          if (nf==KNN){
            minpos=0; minv=bv[0]; mini=bi[0];
            for (int q=1;q<KNN;q++) if (bv[q]<minv || (bv[q]==minv && bi[q]>mini)){minv=bv[q];mini=bi[q];minpos=q;}
          }
        } else if (v>minv || (v==minv && ix<mini)){
          bv[minpos]=v; bi[minpos]=ix;
          minpos=0; minv=bv[0]; mini=bi[0];
          for (int q=1;q<KNN;q++) if (bv[q]<minv || (bv[q]==minv && bi[q]>mini)){minv=bv[q];mini=bi[q];minpos=q;}
        }
      }
    }
    __syncthreads();
  }
  if (t==0){
    for (int aa=1; aa<KNN; aa++){
      float kv=bv[aa]; int ki=bi[aa]; int b=aa-1;
      while (b>=0 && (bv[b]<kv || (bv[b]==kv && bi[b]>ki))){ bv[b+1]=bv[b]; bi[b+1]=bi[b]; b--; }
      bv[b+1]=kv; bi[b+1]=ki;
    }
    for (int q=0;q<KNN;q++){ nbr_idx[(size_t)row*KNN+q]=bi[q]; float v=bv[q]; nbr_w[(size_t)row*KNN+q]=v*v*v; }
  }
}

// ---------------- reverse adjacency ----------------
__global__ void k_indeg(const int* __restrict__ nbr_idx, int* __restrict__ indeg){
  int e = blockIdx.x*blockDim.x + threadIdx.x;
  if (e < N_NODES*KNN) atomicAdd(&indeg[nbr_idx[e]], 1);
}
__global__ __launch_bounds__(256) void k_scan(const int* __restrict__ indeg, int* __restrict__ offs){
  int t = threadIdx.x;
  __shared__ int ps[256];
  int base = t*64, s = 0;
  for (int m=0;m<64;m++) s += indeg[base+m];
  ps[t] = s; __syncthreads();
  if (t==0){ int run=0; for (int i=0;i<256;i++){ int tmp=ps[i]; ps[i]=run; run+=tmp; } offs[N_NODES]=run; }
  __syncthreads();
  int run = ps[t];
  for (int m=0;m<64;m++){ offs[base+m]=run; run += indeg[base+m]; }
}
__global__ void k_fill(const int* __restrict__ nbr_idx, const float* __restrict__ nbr_w,
    const int* __restrict__ offs, int* __restrict__ fillc, int* __restrict__ rev_src, float* __restrict__ rev_w){
  int e = blockIdx.x*blockDim.x + threadIdx.x;
  if (e >= N_NODES*KNN) return;
  int i = e / KNN;
  int j = nbr_idx[e];
  int pos = offs[j] + atomicAdd(&fillc[j], 1);
  rev_src[pos] = i;
  rev_w[pos]  = nbr_w[e];
}
__global__ __launch_bounds__(256) void k_sortrev(const int* __restrict__ offs, int* __restrict__ rev_src, float* __restrict__ rev_w){
  __shared__ int   ssrc[4][512];
  __shared__ float swv [4][512];
  int w = threadIdx.x>>6, lane = threadIdx.x&63;
  int node = blockIdx.x*4 + w;
  int e0 = offs[node], e1 = offs[node+1];
  int len = e1 - e0;
  if (len <= 1 || len > 512) return;
  for (int q=lane; q<len; q+=64){ ssrc[w][q]=rev_src[e0+q]; swv[w][q]=rev_w[e0+q]; }
  if (lane==0){
    for (int a=1;a<len;a++){
      int ks=ssrc[w][a]; float kw=swv[w][a]; int b=a-1;
      while (b>=0 && ssrc[w][b]>ks){ ssrc[w][b+1]=ssrc[w][b]; swv[w][b+1]=swv[w][b]; b--; }
      ssrc[w][b+1]=ks; swv[w][b+1]=kw;
    }
  }
  for (int q=lane; q<len; q+=64){ rev_src[e0+q]=ssrc[w][q]; rev_w[e0+q]=swv[w][q]; }
}
__global__ void k_degree(const float* __restrict__ nbr_w, const int* __restrict__ offs,
    const float* __restrict__ rev_w, float* __restrict__ Dinv){
  int i = blockIdx.x*blockDim.x + threadIdx.x;
  if (i >= N_NODES) return;
  float s = 0.f;
  for (int k=0;k<KNN;k++) s += nbr_w[(size_t)i*KNN+k];
  int e0=offs[i], e1=offs[i+1];
  for (int e=e0;e<e1;e++) s += rev_w[e];
  if (s == 0.f) s = 1.f;
  Dinv[i] = 1.0f / sqrtf(s);
}
__global__ void k_normw_fwd(const int* __restrict__ nbr_idx, float* __restrict__ nbr_w, const float* __restrict__ Dinv){
  int e = blockIdx.x*blockDim.x + threadIdx.x;
  if (e >= N_NODES*KNN) return;
  int i = e / KNN; int j = nbr_idx[e];
  nbr_w[e] *= Dinv[i]*Dinv[j];
}
__global__ __launch_bounds__(256) void k_normw_rev(const int* __restrict__ offs, const int* __restrict__ rev_src,
    float* __restrict__ rev_w, const float* __restrict__ Dinv){
  int wid = (blockIdx.x*256 + threadIdx.x)>>6; int lane = threadIdx.x&63;
  if (wid >= N_NODES) return;
  float di = Dinv[wid];
  int e1 = offs[wid+1];
  for (int e=offs[wid]+lane; e<e1; e+=64) rev_w[e] *= di*Dinv[rev_src[e]];
}
// merged adjacency: node i occupies [50*i+offs[i], 50*(i+1)+offs[i+1]); fwd then rev
__global__ __launch_bounds__(256) void k_pack(const int* __restrict__ nbr_idx, const float* __restrict__ nbr_w,
    const int* __restrict__ offs, const int* __restrict__ rev_src, const float* __restrict__ rev_w,
    int2* __restrict__ adj){
  int w = threadIdx.x>>6, lane = threadIdx.x&63;
  int node = blockIdx.x*4 + w;
  int a0 = 50*node + offs[node];
  for (int k=lane; k<KNN; k+=64)
    adj[a0+k] = make_int2(nbr_idx[(size_t)node*KNN+k], __float_as_int(nbr_w[(size_t)node*KNN+k]));
  int e0 = offs[node], e1 = offs[node+1];
  for (int e=e0+lane; e<e1; e+=64)
    adj[a0+KNN+(e-e0)] = make_int2(rev_src[e], __float_as_int(rev_w[e]));
}

// ---------------- CG setup ----------------
__global__ void k_clscnt(const int* __restrict__ labels, const int* __restrict__ mask, int* __restrict__ cls_cnt){
  int n = blockIdx.x*blockDim.x + threadIdx.x;
  if (n < N_NODES && mask[n]) atomicAdd(&cls_cnt[labels[n]], 1);
}
__global__ void k_init(const int* __restrict__ labels, const int* __restrict__ mask, const int* __restrict__ cls_cnt,
    float* __restrict__ x, float* __restrict__ r, float* __restrict__ p){
  int idx = blockIdx.x*blockDim.x + threadIdx.x;
  if (idx >= N_NODES*PSTR) return;
  int n = idx / PSTR, c = idx - n*PSTR;
  float y = 0.f;
  if (mask[n] && labels[n]==c) y = 1.0f / fmaxf((float)cls_cnt[c], 1.0f);
  x[idx]=0.f; r[idx]=y; p[idx]=y;
}

// ---------------- CG kernels (2048 blocks, 2 nodes/wave, partT[c][2048]) ------
__global__ __launch_bounds__(256) void k_spmv_pap(const float* __restrict__ p, float* __restrict__ Ap,
    const int2* __restrict__ adj, const int* __restrict__ offs,
    float* __restrict__ partT){
  int t = threadIdx.x, w = t>>6, l = t&63;
  __shared__ float sh[4][100];
  float ppx=0.f, ppy=0.f;
  if (l < 50){
    #pragma unroll
    for (int m=0;m<2;m++){
      int node = __builtin_amdgcn_readfirstlane(blockIdx.x*8 + w*2 + m);
      int a0 = 50*node + offs[node];
      int a1 = 50*(node+1) + offs[node+1];
      float accx=0.f, accy=0.f;
      for (int e=a0; e<a1; ++e){
        int2 jw = adj[e];                       // wave-uniform -> s_load
        float wv = __int_as_float(jw.y);
        float2 v = ((const float2*)(p + (size_t)jw.x*PSTR))[l];
        accx = fmaf(wv, v.x, accx);
        accy = fmaf(wv, v.y, accy);
      }
      size_t o = (size_t)node*PSTR;
      float2 pv = ((const float2*)(p + o))[l];
      float ax = pv.x - ALPHA_C*accx;
      float ay = pv.y - ALPHA_C*accy;
      ((float2*)(Ap + o))[l] = make_float2(ax, ay);
      ppx = fmaf(pv.x, ax, ppx);
      ppy = fmaf(pv.y, ay, ppy);
    }
    sh[w][2*l]   = ppx;
    sh[w][2*l+1] = ppy;
  }
  __syncthreads();
  if (t < 100) partT[(size_t)t*NPB + blockIdx.x] = (sh[0][t]+sh[1][t]) + (sh[2][t]+sh[3][t]);
}
__global__ __launch_bounds__(256) void k_alpha(const float* __restrict__ partT, const float* __restrict__ rs_cur,
    const float* __restrict__ bnorm, float* __restrict__ avec, int* __restrict__ actvec){
  int c = blockIdx.x, t = threadIdx.x;
  float s = 0.f;
  #pragma unroll
  for (int b=0;b<NPB/256;b++) s += partT[(size_t)c*NPB + b*256 + t];
  #pragma unroll
  for (int o=1;o<64;o<<=1) s += __shfl_xor(s, o, 64);
  __shared__ float red[4];
  if ((t&63)==0) red[t>>6] = s;
  __syncthreads();
  if (t==0){
    float tot = (red[0]+red[1]) + (red[2]+red[3]);
    float rc = rs_cur[c];
    int act = sqrtf(rc) > TOL_C*fmaxf(bnorm[c], 1e-30f);
    avec[c] = act ? rc/fmaxf(tot, 1e-30f) : 0.f;
    actvec[c] = act;
  }
}
__global__ __launch_bounds__(256) void k_update_xr(float* __restrict__ x, float* __restrict__ r,
    const float* __restrict__ p, const float* __restrict__ Ap,
    const float* __restrict__ avec, float* __restrict__ partT){
  int t = threadIdx.x, w = t>>6, l = t&63;
  __shared__ float sh[4][100];
  float rpx=0.f, rpy=0.f;
  if (l < 50){
    float2 av = ((const float2*)avec)[l];
    #pragma unroll
    for (int m=0;m<2;m++){
      int n = blockIdx.x*8 + w*2 + m;
      size_t o = (size_t)n*PSTR;
      float2 pv  = ((const float2*)(p + o))[l];
      float2 apv = ((const float2*)(Ap + o))[l];
      float2 xv  = ((const float2*)(x + o))[l];
      float2 rv  = ((const float2*)(r + o))[l];
      xv.x = fmaf(av.x, pv.x, xv.x);
      xv.y = fmaf(av.y, pv.y, xv.y);
      rv.x = rv.x - av.x*apv.x;
      rv.y = rv.y - av.y*apv.y;
      ((float2*)(x + o))[l] = xv;
      ((float2*)(r + o))[l] = rv;
      rpx = fmaf(rv.x, rv.x, rpx);
      rpy = fmaf(rv.y, rv.y, rpy);
    }
    sh[w][2*l]   = rpx;
    sh[w][2*l+1] = rpy;
  }
  __syncthreads();
  if (t < 100) partT[(size_t)t*NPB + blockIdx.x] = (sh[0][t]+sh[1][t]) + (sh[2][t]+sh[3][t]);
}
__global__ __launch_bounds__(256) void k_beta(const float* __restrict__ partT, const float* __restrict__ rs_cur,
    const int* __restrict__ actvec, float* __restrict__ rs_next, float* __restrict__ betavec){
  int c = blockIdx.x, t = threadIdx.x;
  float s = 0.f;
  #pragma unroll
  for (int b=0;b<NPB/256;b++) s += partT[(size_t)c*NPB + b*256 + t];
  #pragma unroll
  for (int o=1;o<64;o<<=1) s += __shfl_xor(s, o, 64);
  __shared__ float red[4];
  if ((t&63)==0) red[t>>6] = s;
  __syncthreads();
  if (t==0){
    float tot = (red[0]+red[1]) + (red[2]+red[3]);
    float rc = rs_cur[c];
    int act = actvec[c];
    rs_next[c] = act ? tot : rc;
    betavec[c] = act ? tot/fmaxf(rc, 1e-30f) : 0.f;
  }
}
__global__ __launch_bounds__(256) void k_update_p(float* __restrict__ p, const float* __restrict__ r,
    const int* __restrict__ actvec, const float* __restrict__ betavec){
  int t = threadIdx.x, w = t>>6, l = t&63;
  if (l >= 50) return;
  float2 bv = ((const float2*)betavec)[l];
  int2   av = ((const int2*)actvec)[l];
  #pragma unroll
  for (int m=0;m<2;m++){
    int n = blockIdx.x*8 + w*2 + m;
    size_t o = (size_t)n*PSTR;
    float2 pv = ((const float2*)(p + o))[l];
    float2 rv = ((const float2*)(r + o))[l];
    pv.x = av.x ? fmaf(bv.x, pv.x, rv.x) : pv.x;
    pv.y = av.y ? fmaf(bv.y, pv.y, rv.y) : pv.y;
    ((float2*)(p + o))[l] = pv;
  }
}
// initial rs0 partials from r (=Y)
__global__ __launch_bounds__(256) void k_coldot0(const float* __restrict__ r, float* __restrict__ partT){
  int t = threadIdx.x, w = t>>6, l = t&63;
  __shared__ float sh[4][100];
  float px=0.f, py=0.f;
  if (l < 50){
    #pragma unroll
    for (int m=0;m<2;m++){
      int n = blockIdx.x*8 + w*2 + m;
      float2 rv = ((const float2*)(r + (size_t)n*PSTR))[l];
      px = fmaf(rv.x, rv.x, px);
      py = fmaf(rv.y, rv.y, py);
    }
    sh[w][2*l]   = px;
    sh[w][2*l+1] = py;
  }
  __syncthreads();
  if (t < 100) partT[(size_t)t*NPB + blockIdx.x] = (sh[0][t]+sh[1][t]) + (sh[2][t]+sh[3][t]);
}
__global__ __launch_bounds__(256) void k_rs0(const float* __restrict__ partT, float* __restrict__ rs0, float* __restrict__ bnorm){
  int c = blockIdx.x, t = threadIdx.x;
  float s = 0.f;
  #pragma unroll
  for (int b=0;b<NPB/256;b++) s += partT[(size_t)c*NPB + b*256 + t];
  #pragma unroll
  for (int o=1;o<64;o<<=1) s += __shfl_xor(s, o, 64);
  __shared__ float red[4];
  if ((t&63)==0) red[t>>6] = s;
  __syncthreads();
  if (t==0){
    float tot = (red[0]+red[1]) + (red[2]+red[3]);
    rs0[c] = tot;
    bnorm[c] = sqrtf(tot);
  }
}

// ---------------- finalize ----------------
__global__ __launch_bounds__(256) void k_final(const float* __restrict__ x, const int* __restrict__ labels,
    const int* __restrict__ mask, float* __restrict__ out, int* __restrict__ acc_cnt){
  int n = blockIdx.x*blockDim.x + threadIdx.x;
  if (n >= N_NODES) return;
  const float* xr = x + (size_t)n*PSTR;
  float best = xr[0]; int arg = 0;
  for (int c=1;c<NCLS;c++){ float v = xr[c]; if (v > best){ best = v; arg = c; } }
  int plab = (best > 0.f) ? arg : 0;
  if (plab == labels[n]) atomicAdd(acc_cnt, 1);
  int lab = mask[n] ? labels[n] : plab;
  out[n] = (float)lab;
  out[N_NODES + 1 + n] = 0.f;   // masks provably all-zero
}
__global__ void k_acc(const int* __restrict__ acc_cnt, float* __restrict__ out){
  out[N_NODES] = (float)(*acc_cnt) / (float)N_NODES;
}

// ---------------- host ----------------
extern "C" void kernel_launch(void* const* d_in, const int* in_sizes, int n_in,
                              void* d_out, int out_size, void* d_ws, size_t ws_size,
                              hipStream_t stream){
  (void)in_sizes; (void)n_in; (void)out_size;
  const float* X      = (const float*)d_in[0];
  const int*   labels = (const int*)  d_in[1];
  const int*   mask   = (const int*)  d_in[2];
  float* out = (float*)d_out;

  char* ws = (char*)d_ws;
  size_t off = 0;
  auto alloc = [&](size_t bytes)->char*{ char* pp = ws + off; off += (bytes + 255) & ~(size_t)255; return pp; };

  float* Xn      = (float*)alloc((size_t)N_NODES*DIM*4);
  int*   nbr_idx = (int*)  alloc((size_t)N_NODES*KNN*4);
  float* nbr_w   = (float*)alloc((size_t)N_NODES*KNN*4);
  int*   indeg   = (int*)  alloc((size_t)N_NODES*4);
  int*   offs    = (int*)  alloc((size_t)(N_NODES+1)*4);
  int*   fillc   = (int*)  alloc((size_t)N_NODES*4);
  int*   rev_src = (int*)  alloc((size_t)N_NODES*KNN*4);
  float* rev_w   = (float*)alloc((size_t)N_NODES*KNN*4);
  int2*  adj     = (int2*) alloc((size_t)2*N_NODES*KNN*8);
  float* Dinv    = (float*)alloc((size_t)N_NODES*4);
  int*   cls_cnt = (int*)  alloc(128*4);
  float* x  = (float*)alloc((size_t)N_NODES*PSTR*4);
  float* r  = (float*)alloc((size_t)N_NODES*PSTR*4);
  float* p  = (float*)alloc((size_t)N_NODES*PSTR*4);
  float* Ap = (float*)alloc((size_t)N_NODES*PSTR*4);
  float* rs_a   = (float*)alloc(128*4);
  float* rs_b   = (float*)alloc(128*4);
  float* avec   = (float*)alloc(128*4);
  float* betavec= (float*)alloc(128*4);
  int*   actvec = (int*)  alloc(128*4);
  float* bnorm  = (float*)alloc(128*4);
  float* partT  = (float*)alloc((size_t)100*NPB*4);
  int*   acc_cnt= (int*)  alloc(256);
  int*   flags  = (int*)  alloc((size_t)N_NODES*4);
  int*   cand_cnt=(int*)  alloc((size_t)N_NODES*4);

  size_t rem = (ws_size > off) ? (ws_size - off) : 0;
  size_t capc = rem/((size_t)N_NODES*8);
  int CAP = (int)(capc < 1024 ? capc : 1024);
  CAP &= ~7;   // keep rows 64B-aligned
  unsigned long long* cand = (unsigned long long*)alloc((size_t)N_NODES*CAP*8);

  hipMemsetAsync(cand_cnt, 0, (size_t)N_NODES*4, stream);
  hipMemsetAsync(flags,    0, (size_t)N_NODES*4, stream);
  hipMemsetAsync(indeg,    0, (size_t)N_NODES*4, stream);
  hipMemsetAsync(fillc,    0, (size_t)N_NODES*4, stream);
  hipMemsetAsync(cls_cnt,  0, 128*4, stream);
  hipMemsetAsync(acc_cnt,  0, 4, stream);

  k_norm    <<<N_NODES/2, 256, 0, stream>>>(X, Xn);
  k_sims    <<<NTILE, 256, 0, stream>>>(Xn, cand_cnt, cand, CAP);
  k_select  <<<N_NODES, 256, 0, stream>>>(cand, cand_cnt, CAP, nbr_idx, nbr_w, flags);
  k_fallback<<<N_NODES, 256, 0, stream>>>(Xn, flags, nbr_idx, nbr_w);
  k_indeg   <<<3200, 256, 0, stream>>>(nbr_idx, indeg);
  k_scan    <<<1, 256, 0, stream>>>(indeg, offs);
  k_fill    <<<3200, 256, 0, stream>>>(nbr_idx, nbr_w, offs, fillc, rev_src, rev_w);
  k_sortrev <<<4096, 256, 0, stream>>>(offs, rev_src, rev_w);
  k_degree  <<<64, 256, 0, stream>>>(nbr_w, offs, rev_w, Dinv);
  k_normw_fwd<<<3200, 256, 0, stream>>>(nbr_idx, nbr_w, Dinv);
  k_normw_rev<<<4096, 256, 0, stream>>>(offs, rev_src, rev_w, Dinv);
  k_pack    <<<4096, 256, 0, stream>>>(nbr_idx, nbr_w, offs, rev_src, rev_w, adj);
  k_clscnt  <<<64, 256, 0, stream>>>(labels, mask, cls_cnt);
  k_init    <<<(N_NODES*PSTR+255)/256, 256, 0, stream>>>(labels, mask, cls_cnt, x, r, p);
  k_coldot0 <<<NPB, 256, 0, stream>>>(r, partT);
  k_rs0     <<<100, 256, 0, stream>>>(partT, rs_a, bnorm);

  for (int it=0; it<MAXITER_C; ++it){
    float* rs_cur = (it&1) ? rs_b : rs_a;
    float* rs_nxt = (it&1) ? rs_a : rs_b;
    k_spmv_pap <<<NPB, 256, 0, stream>>>(p, Ap, adj, offs, partT);
    k_alpha    <<<100, 256, 0, stream>>>(partT, rs_cur, bnorm, avec, actvec);
    k_update_xr<<<NPB, 256, 0, stream>>>(x, r, p, Ap, avec, partT);
    if (it < MAXITER_C-1){   // last iter: beta/update_p outputs never consumed
      k_beta     <<<100, 256, 0, stream>>>(partT, rs_cur, actvec, rs_nxt, betavec);
      k_update_p <<<NPB, 256, 0, stream>>>(p, r, actvec, betavec);
    }
  }

  k_final<<<64, 256, 0, stream>>>(x, labels, mask, out, acc_cnt);
  k_acc  <<<1, 1, 0, stream>>>(acc_cnt, out);
}